// Round 3
// baseline (134.001 us; speedup 1.0000x reference)
//
#include <hip/hip_runtime.h>
#include <hip/hip_bf16.h>
#include <math.h>

// Problem constants: B=16, C=128, M=H*W=1024.
#define NB 16
#define NC 128
#define NM 1024
#define KC 32

// Persistent device scratch (fully rewritten every call -> deterministic).
__device__ float    g_T[2][NB * NM * NC];     // token-major copies: T[mat][b][p][c]
__device__ float    g_norm[2][NB * NM];       // ||token||^2 per matrix
__device__ unsigned g_idx[2][NB * NM];        // [0]=idx1 (NN of m1 in m2), [1]=idx2
__device__ float    g_part[3][NM];            // per-position partials: R, S, Qraw
__device__ float    g_rval[NB][4][NM];        // row-min partials over 4 col-splits
__device__ unsigned g_ridx[NB][4][NM];
__device__ float    g_cval[NB][8][NM];        // col-min partials over 8 row-tiles
__device__ unsigned g_cidx[NB][8][NM];

// ---------------------------------------------------------------------------
// Transpose E[b][c][p] (c-major) -> T[b][p][c] (token-major), both matrices.
__global__ __launch_bounds__(256)
void transpose_kernel(const float* __restrict__ e1, const float* __restrict__ e2)
{
    __shared__ float tile[64][65];
    const int z   = blockIdx.z;
    const int b   = z >> 1;
    const int mat = z & 1;
    const float* src = mat ? e2 : e1;
    float*       dst = g_T[mat];
    const int p0 = blockIdx.x * 64;
    const int c0 = blockIdx.y * 64;
    const int tj = threadIdx.x & 63;
    const int ti = threadIdx.x >> 6;     // 0..3
    const float* sb = src + (size_t)b * NC * NM;
    #pragma unroll
    for (int i = 0; i < 16; ++i) {
        int c = i * 4 + ti;
        tile[c][tj] = sb[(size_t)(c0 + c) * NM + p0 + tj];
    }
    __syncthreads();
    float* db = dst + (size_t)b * NM * NC;
    #pragma unroll
    for (int i = 0; i < 16; ++i) {
        int p = i * 4 + ti;
        db[(size_t)(p0 + p) * NC + c0 + tj] = tile[tj][p];
    }
}

// ---------------------------------------------------------------------------
// Token norms directly from the c-major layout (coalesced over p).
__global__ __launch_bounds__(256)
void norm_kernel(const float* __restrict__ e1, const float* __restrict__ e2)
{
    const int z   = blockIdx.x;
    const int mat = z >> 6;
    const int b   = (z >> 2) & 15;
    const int pc  = z & 3;
    const float* src = mat ? e2 : e1;
    const int p = pc * 256 + threadIdx.x;
    const float* sb = src + (size_t)b * NC * NM + p;
    float s = 0.f;
    #pragma unroll 4
    for (int c = 0; c < NC; ++c) {
        float v = sb[(size_t)c * NM];
        s += v * v;
    }
    g_norm[mat][b * NM + p] = s;
}

// ---------------------------------------------------------------------------
// Shared-S argmin with reg-staged double-buffered pipeline (T14 style):
// per phase, issue next chunk's global loads into registers, compute the
// current LDS chunk, ds_write the regs, ONE barrier. 8 phases = 2 col-tiles
// x 4 k-chunks of 32. Row direction (idx1) and col direction (idx2) both
// derived from the same dot-product tiles.
__global__ __launch_bounds__(256, 2)
void argmin3_kernel(const float* __restrict__ e1, const float* __restrict__ e2)
{
    __shared__ float lA[2][KC * 128];
    __shared__ float lB[2][KC * 128];
    __shared__ float    s_cv[4][128];
    __shared__ unsigned s_ci[4][128];

    const int blk = blockIdx.x;          // 512 = 16b * 8rt * 4cs
    const int b  = blk >> 5;
    const int rt = (blk >> 2) & 7;
    const int cs = blk & 3;
    const int m0 = rt << 7;
    const int n0 = cs << 8;
    const int t  = threadIdx.x;
    const int tx = t & 15, ty = t >> 4;

    const float* Ab = e1 + (size_t)b * NC * NM;
    const float* Bb = e2 + (size_t)b * NC * NM;
    const float* nA = &g_norm[0][b * NM];   // ||m1||^2 (col direction)
    const float* nB = &g_norm[1][b * NM];   // ||m2||^2 (row direction)

    // this thread's 8 local row indices' norms
    float rn[8];
    #pragma unroll
    for (int i = 0; i < 8; ++i) {
        int r = (i < 4) ? (ty * 4 + i) : (64 + ty * 4 + i - 4);
        rn[i] = nA[m0 + r];
    }

    float rv[8]; unsigned ri[8];
    #pragma unroll
    for (int i = 0; i < 8; ++i) { rv[i] = 3.4e38f; ri[i] = 0u; }

    float4 ra[4], rb[4];

    // ---- prologue: stage phase 0 (nt=0, kc=0) into buf 0
    #pragma unroll
    for (int i = 0; i < 4; ++i) {
        int f = i * 256 + t;                  // float4-chunk index 0..1023
        int k = f >> 5, r4 = (f & 31) * 4;
        ra[i] = *reinterpret_cast<const float4*>(Ab + (size_t)k * NM + m0 + r4);
        rb[i] = *reinterpret_cast<const float4*>(Bb + (size_t)k * NM + n0 + r4);
    }
    #pragma unroll
    for (int i = 0; i < 4; ++i) {
        int f = i * 256 + t;
        int k = f >> 5, r4 = (f & 31) * 4;
        *reinterpret_cast<float4*>(&lA[0][k * 128 + r4]) = ra[i];
        *reinterpret_cast<float4*>(&lB[0][k * 128 + r4]) = rb[i];
    }
    __syncthreads();

    float acc[8][8] = {};

    for (int p = 0; p < 8; ++p) {
        const int cur = p & 1;
        // ---- issue-early: global loads for phase p+1 (hidden under compute)
        if (p < 7) {
            const int pn = p + 1;
            const int kb = (pn & 3) * KC;
            const int nb = n0 + (pn >> 2) * 128;
            #pragma unroll
            for (int i = 0; i < 4; ++i) {
                int f = i * 256 + t;
                int k = f >> 5, r4 = (f & 31) * 4;
                ra[i] = *reinterpret_cast<const float4*>(Ab + (size_t)(kb + k) * NM + m0 + r4);
                rb[i] = *reinterpret_cast<const float4*>(Bb + (size_t)(kb + k) * NM + nb + r4);
            }
        }
        // ---- compute current chunk
        {
            const float* A = lA[cur];
            const float* B = lB[cur];
            #pragma unroll 4
            for (int k = 0; k < KC; ++k) {
                float4 a0 = *reinterpret_cast<const float4*>(&A[k * 128 + ty * 4]);
                float4 a1 = *reinterpret_cast<const float4*>(&A[k * 128 + 64 + ty * 4]);
                float4 b0 = *reinterpret_cast<const float4*>(&B[k * 128 + tx * 4]);
                float4 b1 = *reinterpret_cast<const float4*>(&B[k * 128 + 64 + tx * 4]);
                float a8[8] = {a0.x, a0.y, a0.z, a0.w, a1.x, a1.y, a1.z, a1.w};
                float b8[8] = {b0.x, b0.y, b0.z, b0.w, b1.x, b1.y, b1.z, b1.w};
                #pragma unroll
                for (int i = 0; i < 8; ++i)
                    #pragma unroll
                    for (int j = 0; j < 8; ++j)
                        acc[i][j] += a8[i] * b8[j];
            }
        }
        // ---- write-late: regs -> other buffer
        if (p < 7) {
            const int nxt = cur ^ 1;
            #pragma unroll
            for (int i = 0; i < 4; ++i) {
                int f = i * 256 + t;
                int k = f >> 5, r4 = (f & 31) * 4;
                *reinterpret_cast<float4*>(&lA[nxt][k * 128 + r4]) = ra[i];
                *reinterpret_cast<float4*>(&lB[nxt][k * 128 + r4]) = rb[i];
            }
        }
        __syncthreads();

        // ---- end of a col-tile: extract row/col minima from acc
        if ((p & 3) == 3) {
            const int nt = p >> 2;
            const int nbase = n0 + nt * 128;
            // row-min update (n ascending; strict < keeps lowest n)
            #pragma unroll
            for (int j = 0; j < 8; ++j) {
                int c = (j < 4) ? (tx * 4 + j) : (64 + tx * 4 + j - 4);
                int n = nbase + c;
                float nv = nB[n];
                #pragma unroll
                for (int i = 0; i < 8; ++i) {
                    float val = nv - 2.0f * acc[i][j];
                    if (val < rv[i]) { rv[i] = val; ri[i] = (unsigned)n; }
                }
            }
            // col-min partial (m ascending within thread)
            float cv[8]; unsigned ci[8];
            #pragma unroll
            for (int j = 0; j < 8; ++j) { cv[j] = 3.4e38f; ci[j] = 0u; }
            #pragma unroll
            for (int i = 0; i < 8; ++i) {
                int r = (i < 4) ? (ty * 4 + i) : (64 + ty * 4 + i - 4);
                int m = m0 + r;
                #pragma unroll
                for (int j = 0; j < 8; ++j) {
                    float val = rn[i] - 2.0f * acc[i][j];
                    if (val < cv[j]) { cv[j] = val; ci[j] = (unsigned)m; }
                }
            }
            // reduce across the 4 ty-groups within each wave
            #pragma unroll
            for (int off = 16; off <= 32; off <<= 1) {
                #pragma unroll
                for (int j = 0; j < 8; ++j) {
                    float    ov = __shfl_xor(cv[j], off);
                    unsigned oi = __shfl_xor(ci[j], off);
                    if (ov < cv[j] || (ov == cv[j] && oi < ci[j])) { cv[j] = ov; ci[j] = oi; }
                }
            }
            const int wv = t >> 6;
            if ((t & 63) < 16) {
                #pragma unroll
                for (int j = 0; j < 8; ++j) {
                    int c = (j < 4) ? (tx * 4 + j) : (64 + tx * 4 + j - 4);
                    s_cv[wv][c] = cv[j]; s_ci[wv][c] = ci[j];
                }
            }
            __syncthreads();
            if (t < 128) {
                float v = s_cv[0][t]; unsigned id = s_ci[0][t];
                #pragma unroll
                for (int w = 1; w < 4; ++w) {
                    float ov = s_cv[w][t]; unsigned oi = s_ci[w][t];
                    if (ov < v || (ov == v && oi < id)) { v = ov; id = oi; }
                }
                g_cval[b][rt][nbase + t] = v;
                g_cidx[b][rt][nbase + t] = id;
            }
            if (p < 7) {
                #pragma unroll
                for (int i = 0; i < 8; ++i)
                    #pragma unroll
                    for (int j = 0; j < 8; ++j)
                        acc[i][j] = 0.f;
            }
            // next phase's __syncthreads (or kernel end) separates s_cv reuse
        }
    }

    // row-min reduce across tx (16-lane groups), lowest-index tie-break
    #pragma unroll
    for (int off = 8; off >= 1; off >>= 1) {
        #pragma unroll
        for (int i = 0; i < 8; ++i) {
            float    ov = __shfl_xor(rv[i], off);
            unsigned oi = __shfl_xor(ri[i], off);
            if (ov < rv[i] || (ov == rv[i] && oi < ri[i])) { rv[i] = ov; ri[i] = oi; }
        }
    }
    if (tx == 0) {
        #pragma unroll
        for (int i = 0; i < 8; ++i) {
            int r = (i < 4) ? (ty * 4 + i) : (64 + ty * 4 + i - 4);
            g_rval[b][cs][m0 + r] = rv[i];
            g_ridx[b][cs][m0 + r] = ri[i];
        }
    }
}

// ---------------------------------------------------------------------------
// Combine partials: blocks 0..63 do row direction (idx1), 64..127 col (idx2).
__global__ __launch_bounds__(256)
void minreduce_kernel()
{
    int gid = blockIdx.x * 256 + threadIdx.x;   // 0..32767
    if (gid < 16384) {
        int b = gid >> 10, m = gid & 1023;
        float v = g_rval[b][0][m]; unsigned id = g_ridx[b][0][m];
        #pragma unroll
        for (int cs = 1; cs < 4; ++cs) {
            float ov = g_rval[b][cs][m]; unsigned oi = g_ridx[b][cs][m];
            if (ov < v || (ov == v && oi < id)) { v = ov; id = oi; }
        }
        g_idx[0][b * NM + m] = id;
    } else {
        int g2 = gid - 16384;
        int b = g2 >> 10, n = g2 & 1023;
        float v = g_cval[b][0][n]; unsigned id = g_cidx[b][0][n];
        #pragma unroll
        for (int rt = 1; rt < 8; ++rt) {
            float ov = g_cval[b][rt][n]; unsigned oi = g_cidx[b][rt][n];
            if (ov < v || (ov == v && oi < id)) { v = ov; id = oi; }
        }
        g_idx[1][b * NM + n] = id;
    }
}

// ---------------------------------------------------------------------------
// Per-position losses. One block per position m. Mats: 0=m1, 1=nn1, 2=m2, 3=nn2.
__global__ __launch_bounds__(256)
void loss_kernel()
{
    __shared__ float Z[4 * 16 * 129];    // stride 129 kills bank conflicts
    __shared__ float red[12];
    const float* T1 = g_T[0];
    const float* T2 = g_T[1];
    const int m = blockIdx.x;
    const int t = threadIdx.x;

    #pragma unroll
    for (int i = 0; i < 8; ++i) {
        int idx = t + i * 256;           // 0..2047
        int b = idx >> 7, c = idx & 127;
        unsigned r1 = g_idx[0][b * NM + m];
        unsigned r2 = g_idx[1][b * NM + m];
        Z[0 * 2064 + b * 129 + c] = T1[((size_t)b * NM + m)  * NC + c];
        Z[1 * 2064 + b * 129 + c] = T2[((size_t)b * NM + r1) * NC + c];
        Z[2 * 2064 + b * 129 + c] = T2[((size_t)b * NM + m)  * NC + c];
        Z[3 * 2064 + b * 129 + c] = T1[((size_t)b * NM + r2) * NC + c];
    }
    __syncthreads();

    // repr loss partial (uncentered)
    float racc = 0.f;
    #pragma unroll
    for (int i = 0; i < 8; ++i) {
        int idx = t + i * 256;
        int b = idx >> 7, c = idx & 127;
        float d0 = Z[0 * 2064 + b * 129 + c] - Z[1 * 2064 + b * 129 + c];
        float d1 = Z[2 * 2064 + b * 129 + c] - Z[3 * 2064 + b * 129 + c];
        racc += d0 * d0 + d1 * d1;
    }
    __syncthreads();                     // repr reads before centering writes

    // column stats: center in place, variance, std-loss, diag² accumulation
    float sacc = 0.f, qdacc = 0.f;
    #pragma unroll
    for (int pass = 0; pass < 2; ++pass) {
        int mat = (t >> 7) + pass * 2;
        int c   = t & 127;
        float* Zm = &Z[mat * 2064];
        float mu = 0.f;
        #pragma unroll
        for (int b = 0; b < 16; ++b) mu += Zm[b * 129 + c];
        mu *= 0.0625f;
        float d = 0.f;
        #pragma unroll
        for (int b = 0; b < 16; ++b) {
            float v = Zm[b * 129 + c] - mu;
            Zm[b * 129 + c] = v;
            d += v * v;
        }
        float stdv = sqrtf(d * (1.0f / 15.0f) + 1e-4f);
        sacc  += fmaxf(1.0f - stdv, 0.f);
        qdacc += d * d;
    }
    __syncthreads();

    // 16x16 Gram per matrix: ||X^T X||_F^2 == ||X X^T||_F^2
    float qaacc = 0.f;
    const int gi = t >> 4, gj = t & 15;
    #pragma unroll
    for (int mat = 0; mat < 4; ++mat) {
        const float* Zi = &Z[mat * 2064 + gi * 129];
        const float* Zj = &Z[mat * 2064 + gj * 129];
        float g = 0.f;
        #pragma unroll 8
        for (int c = 0; c < NC; ++c) g += Zi[c] * Zj[c];
        qaacc += g * g;
    }

    // block-reduce the three partials
    float v0 = racc, v1 = sacc, v2 = qaacc - qdacc;
    #pragma unroll
    for (int off = 32; off >= 1; off >>= 1) {
        v0 += __shfl_xor(v0, off);
        v1 += __shfl_xor(v1, off);
        v2 += __shfl_xor(v2, off);
    }
    const int w = t >> 6;
    if ((t & 63) == 0) { red[w] = v0; red[4 + w] = v1; red[8 + w] = v2; }
    __syncthreads();
    if (t == 0) {
        g_part[0][m] = red[0] + red[1] + red[2] + red[3];
        g_part[1][m] = red[4] + red[5] + red[6] + red[7];
        g_part[2][m] = red[8] + red[9] + red[10] + red[11];
    }
}

// ---------------------------------------------------------------------------
__global__ __launch_bounds__(256)
void final_kernel(float* __restrict__ out)
{
    const int t = threadIdx.x;
    float r = 0.f, s = 0.f, q = 0.f;
    for (int i = t; i < NM; i += 256) {
        r += g_part[0][i];
        s += g_part[1][i];
        q += g_part[2][i];
    }
    __shared__ float red[12];
    #pragma unroll
    for (int off = 32; off >= 1; off >>= 1) {
        r += __shfl_xor(r, off);
        s += __shfl_xor(s, off);
        q += __shfl_xor(q, off);
    }
    const int w = t >> 6;
    if ((t & 63) == 0) { red[w] = r; red[4 + w] = s; red[8 + w] = q; }
    __syncthreads();
    if (t == 0) {
        r = red[0] + red[1] + red[2] + red[3];
        s = red[4] + red[5] + red[6] + red[7];
        q = red[8] + red[9] + red[10] + red[11];
        out[0] = r * (25.0f / 4194304.0f);
        out[1] = s * (25.0f / 524288.0f);
        out[2] = q * (1.0f / (225.0f * 1024.0f * 512.0f));
    }
}

// ---------------------------------------------------------------------------
extern "C" void kernel_launch(void* const* d_in, const int* in_sizes, int n_in,
                              void* d_out, int out_size, void* d_ws, size_t ws_size,
                              hipStream_t stream)
{
    const float* e1 = (const float*)d_in[0];
    const float* e2 = (const float*)d_in[1];
    float* out = (float*)d_out;

    transpose_kernel<<<dim3(16, 2, 32), 256, 0, stream>>>(e1, e2);
    norm_kernel<<<128, 256, 0, stream>>>(e1, e2);
    argmin3_kernel<<<512, 256, 0, stream>>>(e1, e2);
    minreduce_kernel<<<128, 256, 0, stream>>>();
    loss_kernel<<<1024, 256, 0, stream>>>();
    final_kernel<<<1, 256, 0, stream>>>(out);
}

// Round 4
// 129.170 us; speedup vs baseline: 1.0374x; 1.0374x over previous
//
#include <hip/hip_runtime.h>
#include <hip/hip_bf16.h>
#include <math.h>

// Problem constants: B=16, C=128, M=H*W=1024.
#define NB 16
#define NC 128
#define NM 1024
#define KC 16

// Persistent device scratch (fully rewritten every call -> deterministic).
__device__ float    g_T[2][NB * NM * NC];     // token-major copies: T[mat][b][p][c]
__device__ float    g_norm[2][NB * NM];       // ||token||^2 per matrix
__device__ unsigned g_idx[2][NB * NM];        // [0]=idx1 (NN of m1 in m2), [1]=idx2
__device__ float    g_part[3][NM];            // per-position partials: R, S, Qraw
__device__ float    g_rval[NB][8][NM];        // row-min partials over 8 col-splits
__device__ unsigned g_ridx[NB][8][NM];
__device__ float    g_cval[NB][8][NM];        // col-min partials over 8 row-tiles
__device__ unsigned g_cidx[NB][8][NM];

// ---------------------------------------------------------------------------
// Transpose E[b][c][p] (c-major) -> T[b][p][c] (token-major), both matrices.
__global__ __launch_bounds__(256)
void transpose_kernel(const float* __restrict__ e1, const float* __restrict__ e2)
{
    __shared__ float tile[64][65];
    const int z   = blockIdx.z;
    const int b   = z >> 1;
    const int mat = z & 1;
    const float* src = mat ? e2 : e1;
    float*       dst = g_T[mat];
    const int p0 = blockIdx.x * 64;
    const int c0 = blockIdx.y * 64;
    const int tj = threadIdx.x & 63;
    const int ti = threadIdx.x >> 6;     // 0..3
    const float* sb = src + (size_t)b * NC * NM;
    #pragma unroll
    for (int i = 0; i < 16; ++i) {
        int c = i * 4 + ti;
        tile[c][tj] = sb[(size_t)(c0 + c) * NM + p0 + tj];
    }
    __syncthreads();
    float* db = dst + (size_t)b * NM * NC;
    #pragma unroll
    for (int i = 0; i < 16; ++i) {
        int p = i * 4 + ti;
        db[(size_t)(p0 + p) * NC + c0 + tj] = tile[tj][p];
    }
}

// ---------------------------------------------------------------------------
// Token norms directly from the c-major layout (coalesced over p).
__global__ __launch_bounds__(256)
void norm_kernel(const float* __restrict__ e1, const float* __restrict__ e2)
{
    const int z   = blockIdx.x;
    const int mat = z >> 6;
    const int b   = (z >> 2) & 15;
    const int pc  = z & 3;
    const float* src = mat ? e2 : e1;
    const int p = pc * 256 + threadIdx.x;
    const float* sb = src + (size_t)b * NC * NM + p;
    float s = 0.f;
    #pragma unroll 4
    for (int c = 0; c < NC; ++c) {
        float v = sb[(size_t)c * NM];
        s += v * v;
    }
    g_norm[mat][b * NM + p] = s;
}

// ---------------------------------------------------------------------------
// Shared-S argmin, global_load_lds double-buffered pipeline.
// One 128x128 tile per block: grid = 16b * 8rt * 8cs = 1024 blocks,
// KC=16 k-chunks, 8 phases. Per phase: issue next chunk's global->LDS DMA
// (zero VGPR cost), compute current LDS chunk, ONE barrier (vmcnt drain at
// the barrier is covered by the 2048-FMA compute). LDS 36KB -> 4 blocks/CU.
// Staging layout is linear in thread order, matching global_load_lds's
// wave-uniform-base + lane*16 destination contract.
__global__ __launch_bounds__(256, 4)
void argmin4_kernel(const float* __restrict__ e1, const float* __restrict__ e2)
{
    __shared__ float lA[2][KC * 128];
    __shared__ float lB[2][KC * 128];
    __shared__ float    s_cv[4][128];
    __shared__ unsigned s_ci[4][128];

    const int blk = blockIdx.x;          // 1024 = 16b * 8rt * 8cs
    const int b  = blk >> 6;
    const int rt = (blk >> 3) & 7;
    const int cs = blk & 7;
    const int m0 = rt << 7;
    const int n0 = cs << 7;
    const int t  = threadIdx.x;
    const int tx = t & 15, ty = t >> 4;
    const int w  = t >> 6;               // wave id (uniform per wave)

    const float* Ab = e1 + (size_t)b * NC * NM;
    const float* Bb = e2 + (size_t)b * NC * NM;
    const float* nA = &g_norm[0][b * NM];   // ||m1||^2 (col direction)
    const float* nB = &g_norm[1][b * NM];   // ||m2||^2 (row direction)

// Stage k-chunk [kb, kb+KC) into buffer `buf`: 512 16B-chunks per matrix,
// chunk f = i*256 + t -> LDS float offset f*4 (linear), global per-lane addr.
#define STAGE(buf, kb) do {                                                   \
    _Pragma("unroll")                                                         \
    for (int i_ = 0; i_ < 2; ++i_) {                                          \
        int f_ = i_ * 256 + t;                                                \
        int k_ = f_ >> 5, r4_ = (f_ & 31) * 4;                                \
        __builtin_amdgcn_global_load_lds(                                     \
            (__attribute__((address_space(1))) void*)(Ab + (size_t)((kb) + k_) * NM + m0 + r4_), \
            (__attribute__((address_space(3))) void*)&lA[buf][(i_ * 256 + w * 64) * 4], \
            16, 0, 0);                                                        \
        __builtin_amdgcn_global_load_lds(                                     \
            (__attribute__((address_space(1))) void*)(Bb + (size_t)((kb) + k_) * NM + n0 + r4_), \
            (__attribute__((address_space(3))) void*)&lB[buf][(i_ * 256 + w * 64) * 4], \
            16, 0, 0);                                                        \
    }                                                                         \
} while (0)

    STAGE(0, 0);
    __syncthreads();

    float acc[8][8] = {};
    for (int p = 0; p < 8; ++p) {
        const int cur = p & 1;
        if (p < 7) STAGE(cur ^ 1, (p + 1) * KC);
        const float* A = lA[cur];
        const float* B = lB[cur];
        #pragma unroll 4
        for (int k = 0; k < KC; ++k) {
            float4 a0 = *reinterpret_cast<const float4*>(&A[k * 128 + ty * 4]);
            float4 a1 = *reinterpret_cast<const float4*>(&A[k * 128 + 64 + ty * 4]);
            float4 b0 = *reinterpret_cast<const float4*>(&B[k * 128 + tx * 4]);
            float4 b1 = *reinterpret_cast<const float4*>(&B[k * 128 + 64 + tx * 4]);
            float a8[8] = {a0.x, a0.y, a0.z, a0.w, a1.x, a1.y, a1.z, a1.w};
            float b8[8] = {b0.x, b0.y, b0.z, b0.w, b1.x, b1.y, b1.z, b1.w};
            #pragma unroll
            for (int i = 0; i < 8; ++i)
                #pragma unroll
                for (int j = 0; j < 8; ++j)
                    acc[i][j] += a8[i] * b8[j];
        }
        __syncthreads();
    }
#undef STAGE

    // ---- row-min over this block's 128 cols (n ascending; strict < keeps
    // lowest n, matching jnp.argmin)
    float rv[8]; unsigned ri[8];
    #pragma unroll
    for (int i = 0; i < 8; ++i) { rv[i] = 3.4e38f; ri[i] = 0u; }
    #pragma unroll
    for (int j = 0; j < 8; ++j) {
        int c = (j < 4) ? (tx * 4 + j) : (64 + tx * 4 + j - 4);
        int n = n0 + c;
        float nv = nB[n];
        #pragma unroll
        for (int i = 0; i < 8; ++i) {
            float val = nv - 2.0f * acc[i][j];
            if (val < rv[i]) { rv[i] = val; ri[i] = (unsigned)n; }
        }
    }

    // ---- col-min partial (m ascending within thread)
    float cv[8]; unsigned ci[8];
    #pragma unroll
    for (int j = 0; j < 8; ++j) { cv[j] = 3.4e38f; ci[j] = 0u; }
    #pragma unroll
    for (int i = 0; i < 8; ++i) {
        int r = (i < 4) ? (ty * 4 + i) : (64 + ty * 4 + i - 4);
        int m = m0 + r;
        float nv = nA[m];
        #pragma unroll
        for (int j = 0; j < 8; ++j) {
            float val = nv - 2.0f * acc[i][j];
            if (val < cv[j]) { cv[j] = val; ci[j] = (unsigned)m; }
        }
    }
    // reduce across the 4 ty-groups within each wave
    #pragma unroll
    for (int off = 16; off <= 32; off <<= 1) {
        #pragma unroll
        for (int j = 0; j < 8; ++j) {
            float    ov = __shfl_xor(cv[j], off);
            unsigned oi = __shfl_xor(ci[j], off);
            if (ov < cv[j] || (ov == cv[j] && oi < ci[j])) { cv[j] = ov; ci[j] = oi; }
        }
    }
    if ((t & 63) < 16) {
        #pragma unroll
        for (int j = 0; j < 8; ++j) {
            int c = (j < 4) ? (tx * 4 + j) : (64 + tx * 4 + j - 4);
            s_cv[w][c] = cv[j]; s_ci[w][c] = ci[j];
        }
    }
    __syncthreads();
    if (t < 128) {
        float v = s_cv[0][t]; unsigned id = s_ci[0][t];
        #pragma unroll
        for (int wv = 1; wv < 4; ++wv) {
            float ov = s_cv[wv][t]; unsigned oi = s_ci[wv][t];
            if (ov < v || (ov == v && oi < id)) { v = ov; id = oi; }
        }
        g_cval[b][rt][n0 + t] = v;
        g_cidx[b][rt][n0 + t] = id;
    }

    // ---- row-min reduce across tx (16-lane groups), lowest-index tie-break
    #pragma unroll
    for (int off = 8; off >= 1; off >>= 1) {
        #pragma unroll
        for (int i = 0; i < 8; ++i) {
            float    ov = __shfl_xor(rv[i], off);
            unsigned oi = __shfl_xor(ri[i], off);
            if (ov < rv[i] || (ov == rv[i] && oi < ri[i])) { rv[i] = ov; ri[i] = oi; }
        }
    }
    if (tx == 0) {
        #pragma unroll
        for (int i = 0; i < 8; ++i) {
            int r = (i < 4) ? (ty * 4 + i) : (64 + ty * 4 + i - 4);
            g_rval[b][cs][m0 + r] = rv[i];
            g_ridx[b][cs][m0 + r] = ri[i];
        }
    }
}

// ---------------------------------------------------------------------------
// Combine partials: gid<16384 row direction (idx1, over 8 cs), else col (idx2,
// over 8 rt). Ascending split order + tie-break keeps lowest index.
__global__ __launch_bounds__(256)
void minreduce_kernel()
{
    int gid = blockIdx.x * 256 + threadIdx.x;   // 0..32767
    if (gid < 16384) {
        int b = gid >> 10, m = gid & 1023;
        float v = g_rval[b][0][m]; unsigned id = g_ridx[b][0][m];
        #pragma unroll
        for (int cs = 1; cs < 8; ++cs) {
            float ov = g_rval[b][cs][m]; unsigned oi = g_ridx[b][cs][m];
            if (ov < v || (ov == v && oi < id)) { v = ov; id = oi; }
        }
        g_idx[0][b * NM + m] = id;
    } else {
        int g2 = gid - 16384;
        int b = g2 >> 10, n = g2 & 1023;
        float v = g_cval[b][0][n]; unsigned id = g_cidx[b][0][n];
        #pragma unroll
        for (int rt = 1; rt < 8; ++rt) {
            float ov = g_cval[b][rt][n]; unsigned oi = g_cidx[b][rt][n];
            if (ov < v || (ov == v && oi < id)) { v = ov; id = oi; }
        }
        g_idx[1][b * NM + n] = id;
    }
}

// ---------------------------------------------------------------------------
// Per-position losses. One block per position m. Mats: 0=m1, 1=nn1, 2=m2, 3=nn2.
__global__ __launch_bounds__(256)
void loss_kernel()
{
    __shared__ float Z[4 * 16 * 129];    // stride 129 kills bank conflicts
    __shared__ float red[12];
    const float* T1 = g_T[0];
    const float* T2 = g_T[1];
    const int m = blockIdx.x;
    const int t = threadIdx.x;

    #pragma unroll
    for (int i = 0; i < 8; ++i) {
        int idx = t + i * 256;           // 0..2047
        int b = idx >> 7, c = idx & 127;
        unsigned r1 = g_idx[0][b * NM + m];
        unsigned r2 = g_idx[1][b * NM + m];
        Z[0 * 2064 + b * 129 + c] = T1[((size_t)b * NM + m)  * NC + c];
        Z[1 * 2064 + b * 129 + c] = T2[((size_t)b * NM + r1) * NC + c];
        Z[2 * 2064 + b * 129 + c] = T2[((size_t)b * NM + m)  * NC + c];
        Z[3 * 2064 + b * 129 + c] = T1[((size_t)b * NM + r2) * NC + c];
    }
    __syncthreads();

    // repr loss partial (uncentered)
    float racc = 0.f;
    #pragma unroll
    for (int i = 0; i < 8; ++i) {
        int idx = t + i * 256;
        int b = idx >> 7, c = idx & 127;
        float d0 = Z[0 * 2064 + b * 129 + c] - Z[1 * 2064 + b * 129 + c];
        float d1 = Z[2 * 2064 + b * 129 + c] - Z[3 * 2064 + b * 129 + c];
        racc += d0 * d0 + d1 * d1;
    }
    __syncthreads();                     // repr reads before centering writes

    // column stats: center in place, variance, std-loss, diag² accumulation
    float sacc = 0.f, qdacc = 0.f;
    #pragma unroll
    for (int pass = 0; pass < 2; ++pass) {
        int mat = (t >> 7) + pass * 2;
        int c   = t & 127;
        float* Zm = &Z[mat * 2064];
        float mu = 0.f;
        #pragma unroll
        for (int b = 0; b < 16; ++b) mu += Zm[b * 129 + c];
        mu *= 0.0625f;
        float d = 0.f;
        #pragma unroll
        for (int b = 0; b < 16; ++b) {
            float v = Zm[b * 129 + c] - mu;
            Zm[b * 129 + c] = v;
            d += v * v;
        }
        float stdv = sqrtf(d * (1.0f / 15.0f) + 1e-4f);
        sacc  += fmaxf(1.0f - stdv, 0.f);
        qdacc += d * d;
    }
    __syncthreads();

    // 16x16 Gram per matrix: ||X^T X||_F^2 == ||X X^T||_F^2
    float qaacc = 0.f;
    const int gi = t >> 4, gj = t & 15;
    #pragma unroll
    for (int mat = 0; mat < 4; ++mat) {
        const float* Zi = &Z[mat * 2064 + gi * 129];
        const float* Zj = &Z[mat * 2064 + gj * 129];
        float g = 0.f;
        #pragma unroll 8
        for (int c = 0; c < NC; ++c) g += Zi[c] * Zj[c];
        qaacc += g * g;
    }

    // block-reduce the three partials
    float v0 = racc, v1 = sacc, v2 = qaacc - qdacc;
    #pragma unroll
    for (int off = 32; off >= 1; off >>= 1) {
        v0 += __shfl_xor(v0, off);
        v1 += __shfl_xor(v1, off);
        v2 += __shfl_xor(v2, off);
    }
    const int w = t >> 6;
    if ((t & 63) == 0) { red[w] = v0; red[4 + w] = v1; red[8 + w] = v2; }
    __syncthreads();
    if (t == 0) {
        g_part[0][m] = red[0] + red[1] + red[2] + red[3];
        g_part[1][m] = red[4] + red[5] + red[6] + red[7];
        g_part[2][m] = red[8] + red[9] + red[10] + red[11];
    }
}

// ---------------------------------------------------------------------------
__global__ __launch_bounds__(256)
void final_kernel(float* __restrict__ out)
{
    const int t = threadIdx.x;
    float r = 0.f, s = 0.f, q = 0.f;
    for (int i = t; i < NM; i += 256) {
        r += g_part[0][i];
        s += g_part[1][i];
        q += g_part[2][i];
    }
    __shared__ float red[12];
    #pragma unroll
    for (int off = 32; off >= 1; off >>= 1) {
        r += __shfl_xor(r, off);
        s += __shfl_xor(s, off);
        q += __shfl_xor(q, off);
    }
    const int w = t >> 6;
    if ((t & 63) == 0) { red[w] = r; red[4 + w] = s; red[8 + w] = q; }
    __syncthreads();
    if (t == 0) {
        r = red[0] + red[1] + red[2] + red[3];
        s = red[4] + red[5] + red[6] + red[7];
        q = red[8] + red[9] + red[10] + red[11];
        out[0] = r * (25.0f / 4194304.0f);
        out[1] = s * (25.0f / 524288.0f);
        out[2] = q * (1.0f / (225.0f * 1024.0f * 512.0f));
    }
}

// ---------------------------------------------------------------------------
extern "C" void kernel_launch(void* const* d_in, const int* in_sizes, int n_in,
                              void* d_out, int out_size, void* d_ws, size_t ws_size,
                              hipStream_t stream)
{
    const float* e1 = (const float*)d_in[0];
    const float* e2 = (const float*)d_in[1];
    float* out = (float*)d_out;

    transpose_kernel<<<dim3(16, 2, 32), 256, 0, stream>>>(e1, e2);
    norm_kernel<<<128, 256, 0, stream>>>(e1, e2);
    argmin4_kernel<<<1024, 256, 0, stream>>>(e1, e2);
    minreduce_kernel<<<128, 256, 0, stream>>>();
    loss_kernel<<<1024, 256, 0, stream>>>();
    final_kernel<<<1, 256, 0, stream>>>(out);
}

// Round 5
// 102.568 us; speedup vs baseline: 1.3065x; 1.2594x over previous
//
#include <hip/hip_runtime.h>
#include <hip/hip_bf16.h>
#include <math.h>

// Problem constants: B=16, C=128, M=H*W=1024.
#define NB 16
#define NC 128
#define NM 1024

typedef __attribute__((ext_vector_type(8))) short  short8v;   // 8 bf16 = 4 VGPR
typedef __attribute__((ext_vector_type(16))) float floatx16;  // MFMA 32x32 acc

// Persistent device scratch (fully rewritten every call -> deterministic).
__device__ float    g_T[2][NB * NM * NC];     // token-major fp32: T[mat][b][p][c]
__device__ unsigned short g_FH[2][NB * NM * NC]; // bf16 hi, fragment-linear
__device__ unsigned short g_FL[2][NB * NM * NC]; // bf16 lo, fragment-linear
__device__ float    g_norm[2][NB * NM];       // ||token||^2 per matrix
__device__ unsigned g_idx[2][NB * NM];        // [0]=idx1 (NN of m1 in m2), [1]=idx2
__device__ float    g_part[3][NM];            // per-position partials: R, S, Qraw
__device__ float    g_rval[NB][8][NM];        // row-min partials over 8 col-splits
__device__ unsigned g_ridx[NB][8][NM];
__device__ float    g_cval[NB][8][NM];        // col-min partials over 8 row-tiles
__device__ unsigned g_cidx[NB][8][NM];

// Fragment-linear index: chunk = (b*32 + row/32)*8 + k/16 holds a 1KB wave
// fragment; within it lane = (khalf<<5)|(row&31) holds 8 consecutive k.
__device__ __forceinline__ size_t fidx(int b, int row, int k)
{
    return ((size_t)((b * 32 + (row >> 5)) * 8 + (k >> 4)) * 64
            + (((k >> 3) & 1) << 5) + (row & 31)) * 8 + (k & 7);
}

// ---------------------------------------------------------------------------
// Transpose E[b][c][p] (c-major) -> T[b][p][c] fp32 + bf16 hi/lo fragment-
// linear copies for the MFMA distance GEMM.
__global__ __launch_bounds__(256)
void transpose_kernel(const float* __restrict__ e1, const float* __restrict__ e2)
{
    __shared__ float tile[64][65];
    const int z   = blockIdx.z;
    const int b   = z >> 1;
    const int mat = z & 1;
    const float* src = mat ? e2 : e1;
    float*       dst = g_T[mat];
    const int p0 = blockIdx.x * 64;
    const int c0 = blockIdx.y * 64;
    const int tj = threadIdx.x & 63;
    const int ti = threadIdx.x >> 6;     // 0..3
    const float* sb = src + (size_t)b * NC * NM;
    #pragma unroll
    for (int i = 0; i < 16; ++i) {
        int c = i * 4 + ti;
        tile[c][tj] = sb[(size_t)(c0 + c) * NM + p0 + tj];
    }
    __syncthreads();
    float* db = dst + (size_t)b * NM * NC;
    unsigned short* fh = g_FH[mat];
    unsigned short* fl = g_FL[mat];
    #pragma unroll
    for (int i = 0; i < 16; ++i) {
        int p = i * 4 + ti;                 // value = element(row=p0+p, k=c0+tj)
        float v = tile[tj][p];
        db[(size_t)(p0 + p) * NC + c0 + tj] = v;
        // RNE bf16 split: v = hi + lo (+ O(2^-18 v))
        unsigned xb = __float_as_uint(v);
        unsigned hr = (xb + 0x7FFFu + ((xb >> 16) & 1u)) >> 16;
        float h = __uint_as_float(hr << 16);
        float l = v - h;
        unsigned lb = __float_as_uint(l);
        unsigned lr = (lb + 0x7FFFu + ((lb >> 16) & 1u)) >> 16;
        size_t fi = fidx(b, p0 + p, c0 + tj);
        fh[fi] = (unsigned short)hr;
        fl[fi] = (unsigned short)lr;
    }
}

// ---------------------------------------------------------------------------
// Token norms directly from the c-major layout (coalesced over p).
__global__ __launch_bounds__(256)
void norm_kernel(const float* __restrict__ e1, const float* __restrict__ e2)
{
    const int z   = blockIdx.x;
    const int mat = z >> 6;
    const int b   = (z >> 2) & 15;
    const int pc  = z & 3;
    const float* src = mat ? e2 : e1;
    const int p = pc * 256 + threadIdx.x;
    const float* sb = src + (size_t)b * NC * NM + p;
    float s = 0.f;
    #pragma unroll 4
    for (int c = 0; c < NC; ++c) {
        float v = sb[(size_t)c * NM];
        s += v * v;
    }
    g_norm[mat][b * NM + p] = s;
}

// ---------------------------------------------------------------------------
// MFMA distance-argmin: S = m1 . m2^T via 3-term bf16-split MFMA
// (hi*hi + hi*lo + lo*hi), both argmin directions from the same tiles.
// Block = 128m x 128n, 4 waves; wave w owns rows [m0+32w, m0+32w+32).
// B panel (hi+lo) staged linearly into LDS via global_load_lds; A fragments
// loaded straight to VGPRs (coalesced 1KB wave reads in frag-linear layout).
__global__ __launch_bounds__(256, 2)
void argmin5_kernel()
{
    __shared__ unsigned short lBH[4 * 8 * 512];   // 32 KB
    __shared__ unsigned short lBL[4 * 8 * 512];   // 32 KB
    __shared__ float    s_nA[128], s_nB[128];
    __shared__ float    s_cv[4][128];
    __shared__ unsigned s_ci[4][128];

    const int blk = blockIdx.x;          // 1024 = 16b * 8rt * 8cs
    const int b  = blk >> 6;
    const int rt = (blk >> 3) & 7;
    const int cs = blk & 7;
    const int m0 = rt << 7;
    const int n0 = cs << 7;
    const int t  = threadIdx.x;
    const int w  = t >> 6;
    const int lane = t & 63;
    const int cl   = lane & 31;
    const int half = lane >> 5;

    // ---- stage B panel: rowblks n0/32 .. +4, contiguous 32KB per array
    const size_t bbase = (size_t)((b * 32 + (n0 >> 5)) * 8) * 512;  // ushort
    #pragma unroll
    for (int i = 0; i < 8; ++i) {
        int chunk = i * 256 + t;                 // 0..2047 16B chunks
        __builtin_amdgcn_global_load_lds(
            (__attribute__((address_space(1))) void*)(g_FH[1] + bbase + (size_t)chunk * 8),
            (__attribute__((address_space(3))) void*)&lBH[chunk * 8], 16, 0, 0);
        __builtin_amdgcn_global_load_lds(
            (__attribute__((address_space(1))) void*)(g_FL[1] + bbase + (size_t)chunk * 8),
            (__attribute__((address_space(3))) void*)&lBL[chunk * 8], 16, 0, 0);
    }
    if (t < 128) {
        s_nA[t] = g_norm[0][b * NM + m0 + t];
        s_nB[t] = g_norm[1][b * NM + n0 + t];
    }

    // ---- A fragments straight to registers (not LDS)
    const size_t abase = (size_t)((b * 32 + (m0 >> 5) + w) * 8) * 64 + lane;
    const short8v* FAH = (const short8v*)g_FH[0];
    const short8v* FAL = (const short8v*)g_FL[0];
    short8v aH[8], aL[8];
    #pragma unroll
    for (int s = 0; s < 8; ++s) {
        aH[s] = FAH[abase + s * 64];
        aL[s] = FAL[abase + s * 64];
    }

    __syncthreads();   // drains global_load_lds (compiler emits vmcnt(0))

    // ---- MFMA main: 8 k-steps x 4 n-tiles x 3 split terms
    floatx16 acc[4] = {};
    #pragma unroll
    for (int s = 0; s < 8; ++s) {
        #pragma unroll
        for (int nt = 0; nt < 4; ++nt) {
            const int off = (nt * 8 + s) * 512 + lane * 8;   // lane-linear
            short8v bh = *(const short8v*)&lBH[off];
            short8v bl = *(const short8v*)&lBL[off];
            acc[nt] = __builtin_amdgcn_mfma_f32_32x32x16_bf16(aL[s], bh, acc[nt], 0, 0, 0);
            acc[nt] = __builtin_amdgcn_mfma_f32_32x32x16_bf16(aH[s], bl, acc[nt], 0, 0, 0);
            acc[nt] = __builtin_amdgcn_mfma_f32_32x32x16_bf16(aH[s], bh, acc[nt], 0, 0, 0);
        }
    }

    // C/D map: col = cl (+32*nt), row = (r&3) + 8*(r>>2) + 4*half (+32*w)

    // ---- row direction: per reg (row), min over the 128 cols
    float rv[16]; unsigned ri[16];
    #pragma unroll
    for (int r = 0; r < 16; ++r) { rv[r] = 3.4e38f; ri[r] = 0u; }
    #pragma unroll
    for (int nt = 0; nt < 4; ++nt) {
        unsigned n = (unsigned)(n0 + nt * 32 + cl);
        float nv = s_nB[nt * 32 + cl];
        #pragma unroll
        for (int r = 0; r < 16; ++r) {
            float val = nv - 2.0f * acc[nt][r];
            if (val < rv[r] || (val == rv[r] && n < ri[r])) { rv[r] = val; ri[r] = n; }
        }
    }
    #pragma unroll
    for (int off = 1; off <= 16; off <<= 1) {     // reduce over 32 cols
        #pragma unroll
        for (int r = 0; r < 16; ++r) {
            float    ov = __shfl_xor(rv[r], off);
            unsigned oi = __shfl_xor(ri[r], off);
            if (ov < rv[r] || (ov == rv[r] && oi < ri[r])) { rv[r] = ov; ri[r] = oi; }
        }
    }
    if (cl == 0) {
        #pragma unroll
        for (int r = 0; r < 16; ++r) {
            int mloc = w * 32 + (r & 3) + 8 * (r >> 2) + 4 * half;
            g_rval[b][cs][m0 + mloc] = rv[r];
            g_ridx[b][cs][m0 + mloc] = ri[r];
        }
    }

    // ---- col direction: per (nt, cl) col, min over this wave's 32 rows
    float cv[4]; unsigned ci[4];
    #pragma unroll
    for (int nt = 0; nt < 4; ++nt) { cv[nt] = 3.4e38f; ci[nt] = 0u; }
    #pragma unroll
    for (int r = 0; r < 16; ++r) {
        int mloc = w * 32 + (r & 3) + 8 * (r >> 2) + 4 * half;
        float nv = s_nA[mloc];
        unsigned m = (unsigned)(m0 + mloc);
        #pragma unroll
        for (int nt = 0; nt < 4; ++nt) {
            float val = nv - 2.0f * acc[nt][r];
            if (val < cv[nt] || (val == cv[nt] && m < ci[nt])) { cv[nt] = val; ci[nt] = m; }
        }
    }
    #pragma unroll
    for (int nt = 0; nt < 4; ++nt) {              // combine the two halves
        float    ov = __shfl_xor(cv[nt], 32);
        unsigned oi = __shfl_xor(ci[nt], 32);
        if (ov < cv[nt] || (ov == cv[nt] && oi < ci[nt])) { cv[nt] = ov; ci[nt] = oi; }
    }
    if (half == 0) {
        #pragma unroll
        for (int nt = 0; nt < 4; ++nt) {
            s_cv[w][nt * 32 + cl] = cv[nt];
            s_ci[w][nt * 32 + cl] = ci[nt];
        }
    }
    __syncthreads();
    if (t < 128) {
        float v = s_cv[0][t]; unsigned id = s_ci[0][t];
        #pragma unroll
        for (int wv = 1; wv < 4; ++wv) {
            float ov = s_cv[wv][t]; unsigned oi = s_ci[wv][t];
            if (ov < v || (ov == v && oi < id)) { v = ov; id = oi; }
        }
        g_cval[b][rt][n0 + t] = v;
        g_cidx[b][rt][n0 + t] = id;
    }
}

// ---------------------------------------------------------------------------
// Combine partials: gid<16384 row direction (idx1, over 8 cs), else col (idx2,
// over 8 rt). Explicit value+index tie-break keeps lowest index.
__global__ __launch_bounds__(256)
void minreduce_kernel()
{
    int gid = blockIdx.x * 256 + threadIdx.x;   // 0..32767
    if (gid < 16384) {
        int b = gid >> 10, m = gid & 1023;
        float v = g_rval[b][0][m]; unsigned id = g_ridx[b][0][m];
        #pragma unroll
        for (int cs = 1; cs < 8; ++cs) {
            float ov = g_rval[b][cs][m]; unsigned oi = g_ridx[b][cs][m];
            if (ov < v || (ov == v && oi < id)) { v = ov; id = oi; }
        }
        g_idx[0][b * NM + m] = id;
    } else {
        int g2 = gid - 16384;
        int b = g2 >> 10, n = g2 & 1023;
        float v = g_cval[b][0][n]; unsigned id = g_cidx[b][0][n];
        #pragma unroll
        for (int rt = 1; rt < 8; ++rt) {
            float ov = g_cval[b][rt][n]; unsigned oi = g_cidx[b][rt][n];
            if (ov < v || (ov == v && oi < id)) { v = ov; id = oi; }
        }
        g_idx[1][b * NM + n] = id;
    }
}

// ---------------------------------------------------------------------------
// Per-position losses. One block per position m. Mats: 0=m1, 1=nn1, 2=m2, 3=nn2.
__global__ __launch_bounds__(256)
void loss_kernel()
{
    __shared__ float Z[4 * 16 * 129];    // stride 129 kills bank conflicts
    __shared__ float red[12];
    const float* T1 = g_T[0];
    const float* T2 = g_T[1];
    const int m = blockIdx.x;
    const int t = threadIdx.x;

    #pragma unroll
    for (int i = 0; i < 8; ++i) {
        int idx = t + i * 256;           // 0..2047
        int b = idx >> 7, c = idx & 127;
        unsigned r1 = g_idx[0][b * NM + m];
        unsigned r2 = g_idx[1][b * NM + m];
        Z[0 * 2064 + b * 129 + c] = T1[((size_t)b * NM + m)  * NC + c];
        Z[1 * 2064 + b * 129 + c] = T2[((size_t)b * NM + r1) * NC + c];
        Z[2 * 2064 + b * 129 + c] = T2[((size_t)b * NM + m)  * NC + c];
        Z[3 * 2064 + b * 129 + c] = T1[((size_t)b * NM + r2) * NC + c];
    }
    __syncthreads();

    // repr loss partial (uncentered)
    float racc = 0.f;
    #pragma unroll
    for (int i = 0; i < 8; ++i) {
        int idx = t + i * 256;
        int b = idx >> 7, c = idx & 127;
        float d0 = Z[0 * 2064 + b * 129 + c] - Z[1 * 2064 + b * 129 + c];
        float d1 = Z[2 * 2064 + b * 129 + c] - Z[3 * 2064 + b * 129 + c];
        racc += d0 * d0 + d1 * d1;
    }
    __syncthreads();                     // repr reads before centering writes

    // column stats: center in place, variance, std-loss, diag² accumulation
    float sacc = 0.f, qdacc = 0.f;
    #pragma unroll
    for (int pass = 0; pass < 2; ++pass) {
        int mat = (t >> 7) + pass * 2;
        int c   = t & 127;
        float* Zm = &Z[mat * 2064];
        float mu = 0.f;
        #pragma unroll
        for (int b = 0; b < 16; ++b) mu += Zm[b * 129 + c];
        mu *= 0.0625f;
        float d = 0.f;
        #pragma unroll
        for (int b = 0; b < 16; ++b) {
            float v = Zm[b * 129 + c] - mu;
            Zm[b * 129 + c] = v;
            d += v * v;
        }
        float stdv = sqrtf(d * (1.0f / 15.0f) + 1e-4f);
        sacc  += fmaxf(1.0f - stdv, 0.f);
        qdacc += d * d;
    }
    __syncthreads();

    // 16x16 Gram per matrix: ||X^T X||_F^2 == ||X X^T||_F^2
    float qaacc = 0.f;
    const int gi = t >> 4, gj = t & 15;
    #pragma unroll
    for (int mat = 0; mat < 4; ++mat) {
        const float* Zi = &Z[mat * 2064 + gi * 129];
        const float* Zj = &Z[mat * 2064 + gj * 129];
        float g = 0.f;
        #pragma unroll 8
        for (int c = 0; c < NC; ++c) g += Zi[c] * Zj[c];
        qaacc += g * g;
    }

    // block-reduce the three partials
    float v0 = racc, v1 = sacc, v2 = qaacc - qdacc;
    #pragma unroll
    for (int off = 32; off >= 1; off >>= 1) {
        v0 += __shfl_xor(v0, off);
        v1 += __shfl_xor(v1, off);
        v2 += __shfl_xor(v2, off);
    }
    const int w = t >> 6;
    if ((t & 63) == 0) { red[w] = v0; red[4 + w] = v1; red[8 + w] = v2; }
    __syncthreads();
    if (t == 0) {
        g_part[0][m] = red[0] + red[1] + red[2] + red[3];
        g_part[1][m] = red[4] + red[5] + red[6] + red[7];
        g_part[2][m] = red[8] + red[9] + red[10] + red[11];
    }
}

// ---------------------------------------------------------------------------
__global__ __launch_bounds__(256)
void final_kernel(float* __restrict__ out)
{
    const int t = threadIdx.x;
    float r = 0.f, s = 0.f, q = 0.f;
    for (int i = t; i < NM; i += 256) {
        r += g_part[0][i];
        s += g_part[1][i];
        q += g_part[2][i];
    }
    __shared__ float red[12];
    #pragma unroll
    for (int off = 32; off >= 1; off >>= 1) {
        r += __shfl_xor(r, off);
        s += __shfl_xor(s, off);
        q += __shfl_xor(q, off);
    }
    const int w = t >> 6;
    if ((t & 63) == 0) { red[w] = r; red[4 + w] = s; red[8 + w] = q; }
    __syncthreads();
    if (t == 0) {
        r = red[0] + red[1] + red[2] + red[3];
        s = red[4] + red[5] + red[6] + red[7];
        q = red[8] + red[9] + red[10] + red[11];
        out[0] = r * (25.0f / 4194304.0f);
        out[1] = s * (25.0f / 524288.0f);
        out[2] = q * (1.0f / (225.0f * 1024.0f * 512.0f));
    }
}

// ---------------------------------------------------------------------------
extern "C" void kernel_launch(void* const* d_in, const int* in_sizes, int n_in,
                              void* d_out, int out_size, void* d_ws, size_t ws_size,
                              hipStream_t stream)
{
    const float* e1 = (const float*)d_in[0];
    const float* e2 = (const float*)d_in[1];
    float* out = (float*)d_out;

    transpose_kernel<<<dim3(16, 2, 32), 256, 0, stream>>>(e1, e2);
    norm_kernel<<<128, 256, 0, stream>>>(e1, e2);
    argmin5_kernel<<<1024, 256, 0, stream>>>();
    minreduce_kernel<<<128, 256, 0, stream>>>();
    loss_kernel<<<1024, 256, 0, stream>>>();
    final_kernel<<<1, 256, 0, stream>>>(out);
}

// Round 6
// 100.089 us; speedup vs baseline: 1.3388x; 1.0248x over previous
//
#include <hip/hip_runtime.h>
#include <hip/hip_bf16.h>
#include <math.h>

// Problem constants: B=16, C=128, M=H*W=1024.
#define NB 16
#define NC 128
#define NM 1024
#define ZS 132   // loss LDS row stride (16B-aligned, bank-shifted)

typedef __attribute__((ext_vector_type(8))) short  short8v;   // 8 bf16 = 4 VGPR
typedef __attribute__((ext_vector_type(16))) float floatx16;  // MFMA 32x32 acc

// Persistent device scratch (fully rewritten every call -> deterministic).
// Fragment-linear bf16 hi/lo: chunk = (b*32 + row/32)*8 + k/16 is a 1KB wave
// fragment; within it lane = ((k>>3)&1)*32 | (row&31) holds 8 consecutive k.
__device__ unsigned short g_FH[2][NB * NM * NC]; // bf16 hi
__device__ unsigned short g_FL[2][NB * NM * NC]; // bf16 lo
__device__ float    g_norm[2][NB * NM];       // ||token||^2 per matrix (exact fp32)
__device__ unsigned g_idx[2][NB * NM];        // [0]=idx1 (NN of m1 in m2), [1]=idx2
__device__ float    g_part[3][NM];            // per-position partials: R, S, Qraw
__device__ float    g_rval[NB][8][NM];        // row-min partials over 8 col-splits
__device__ unsigned g_ridx[NB][8][NM];
__device__ float    g_cval[NB][8][NM];        // col-min partials over 8 row-tiles
__device__ unsigned g_cidx[NB][8][NM];

// ---------------------------------------------------------------------------
// Transpose E[b][c][p] (c-major) -> bf16 hi/lo fragment-linear, coalesced 16B
// stores (one 8-k octet per thread-task). No fp32 copy.
__global__ __launch_bounds__(256)
void transpose_kernel(const float* __restrict__ e1, const float* __restrict__ e2)
{
    __shared__ float tile[64][65];
    const int z   = blockIdx.z;
    const int b   = z >> 1;
    const int mat = z & 1;
    const float* src = mat ? e2 : e1;
    const int p0 = blockIdx.x * 64;
    const int c0 = blockIdx.y * 64;
    const int t  = threadIdx.x;
    const int tj = t & 63;
    const int ti = t >> 6;               // 0..3
    const float* sb = src + (size_t)b * NC * NM;
    #pragma unroll
    for (int i = 0; i < 16; ++i) {
        int c = i * 4 + ti;
        tile[c][tj] = sb[(size_t)(c0 + c) * NM + p0 + tj];
    }
    __syncthreads();
    unsigned short* fh = g_FH[mat];
    unsigned short* fl = g_FL[mat];
    #pragma unroll
    for (int it = 0; it < 2; ++it) {
        const int p  = t & 63;
        const int ko = (t >> 6) + it * 4;      // 0..7 k-octet within c-tile
        short8v hv, lv;
        #pragma unroll
        for (int e = 0; e < 8; ++e) {
            float v = tile[ko * 8 + e][p];
            unsigned xb = __float_as_uint(v);
            unsigned hr = (xb + 0x7FFFu + ((xb >> 16) & 1u)) >> 16;
            float h = __uint_as_float(hr << 16);
            float l = v - h;
            unsigned lb = __float_as_uint(l);
            unsigned lr = (lb + 0x7FFFu + ((lb >> 16) & 1u)) >> 16;
            hv[e] = (short)hr;
            lv[e] = (short)lr;
        }
        const int row = p0 + p, k = c0 + ko * 8;
        size_t base = (((size_t)(b * 32 + (row >> 5)) * 8 + (k >> 4)) * 64
                       + ((k >> 3) & 1) * 32 + (row & 31)) * 8;
        *reinterpret_cast<short8v*>(fh + base) = hv;
        *reinterpret_cast<short8v*>(fl + base) = lv;
    }
}

// ---------------------------------------------------------------------------
// Token norms directly from the c-major layout (coalesced over p), exact fp32.
__global__ __launch_bounds__(256)
void norm_kernel(const float* __restrict__ e1, const float* __restrict__ e2)
{
    const int z   = blockIdx.x;
    const int mat = z >> 6;
    const int b   = (z >> 2) & 15;
    const int pc  = z & 3;
    const float* src = mat ? e2 : e1;
    const int p = pc * 256 + threadIdx.x;
    const float* sb = src + (size_t)b * NC * NM + p;
    float s = 0.f;
    #pragma unroll 4
    for (int c = 0; c < NC; ++c) {
        float v = sb[(size_t)c * NM];
        s += v * v;
    }
    g_norm[mat][b * NM + p] = s;
}

// ---------------------------------------------------------------------------
// MFMA distance-argmin, per-nt pipelined. Block = 128m x 128n, 4 waves; wave w
// owns rows [m0+32w, +32). A frags (hi+lo) in VGPRs; B staged per 32-col tile
// (8KB hi + 8KB lo), double-buffered, staged 2 phases ahead (stage issued
// right AFTER the barrier ending a phase -> a full compute phase + barrier of
// latency cover, no counted vmcnt needed). 3-term bf16-split MFMA is exact
// enough that argmins matched fp32 reference bit-exactly in round 5.
__global__ __launch_bounds__(256, 3)
void argmin6_kernel()
{
    __shared__ unsigned short lBH[2][8 * 512];   // 8 KB per buffer
    __shared__ unsigned short lBL[2][8 * 512];
    __shared__ float    s_nA[128], s_nB[128];
    __shared__ float    s_cv[4][128];
    __shared__ unsigned s_ci[4][128];

    const int blk = blockIdx.x;          // 1024 = 16b * 8rt * 8cs
    const int b  = blk >> 6;
    const int rt = (blk >> 3) & 7;
    const int cs = blk & 7;
    const int m0 = rt << 7;
    const int n0 = cs << 7;
    const int t  = threadIdx.x;
    const int w  = t >> 6;
    const int lane = t & 63;
    const int cl   = lane & 31;
    const int half = lane >> 5;

// Stage the 32-col tile (n0 + nt*32): 8 chunks of 512 ushorts, hi+lo.
#define STAGE(buf, nt) do {                                                   \
    const size_t cb_ = ((size_t)(b * 32 + (n0 >> 5) + (nt)) * 8) * 512;       \
    _Pragma("unroll")                                                         \
    for (int i_ = 0; i_ < 2; ++i_) {                                          \
        int f_ = i_ * 256 + t;                                                \
        __builtin_amdgcn_global_load_lds(                                     \
            (__attribute__((address_space(1))) void*)(g_FH[1] + cb_ + (size_t)f_ * 8), \
            (__attribute__((address_space(3))) void*)&lBH[buf][f_ * 8], 16, 0, 0); \
        __builtin_amdgcn_global_load_lds(                                     \
            (__attribute__((address_space(1))) void*)(g_FL[1] + cb_ + (size_t)f_ * 8), \
            (__attribute__((address_space(3))) void*)&lBL[buf][f_ * 8], 16, 0, 0); \
    }                                                                         \
} while (0)

    STAGE(0, 0);
    STAGE(1, 1);
    if (t < 128) {
        s_nA[t] = g_norm[0][b * NM + m0 + t];
        s_nB[t] = g_norm[1][b * NM + n0 + t];
    }

    // A fragments straight to registers (coalesced 1KB wave reads)
    const size_t abase = (size_t)((b * 32 + (m0 >> 5) + w) * 8) * 64 + lane;
    const short8v* FAH = (const short8v*)g_FH[0];
    const short8v* FAL = (const short8v*)g_FL[0];
    short8v aH[8], aL[8];
    #pragma unroll
    for (int s = 0; s < 8; ++s) {
        aH[s] = FAH[abase + s * 64];
        aL[s] = FAL[abase + s * 64];
    }

    float rv[16]; unsigned ri[16];
    #pragma unroll
    for (int r = 0; r < 16; ++r) { rv[r] = 3.4e38f; ri[r] = 0u; }

    __syncthreads();   // drains prologue staging + A loads

    for (int nt = 0; nt < 4; ++nt) {
        const int buf = nt & 1;
        floatx16 acc = {};
        #pragma unroll
        for (int s = 0; s < 8; ++s) {
            const int off = s * 512 + lane * 8;           // lane-linear, no conflicts
            short8v bh = *(const short8v*)&lBH[buf][off];
            short8v bl = *(const short8v*)&lBL[buf][off];
            acc = __builtin_amdgcn_mfma_f32_32x32x16_bf16(aL[s], bh, acc, 0, 0, 0);
            acc = __builtin_amdgcn_mfma_f32_32x32x16_bf16(aH[s], bl, acc, 0, 0, 0);
            acc = __builtin_amdgcn_mfma_f32_32x32x16_bf16(aH[s], bh, acc, 0, 0, 0);
        }
        // C/D map: col = cl (+32*nt), row(reg r) = (r&3)+8*(r>>2)+4*half (+32*w)
        // row direction: n ascending within lane (nt asc, cl fixed) -> strict <
        {
            const float nv = s_nB[nt * 32 + cl];
            const unsigned n = (unsigned)(n0 + nt * 32 + cl);
            #pragma unroll
            for (int r = 0; r < 16; ++r) {
                float val = nv - 2.0f * acc[r];
                if (val < rv[r]) { rv[r] = val; ri[r] = n; }
            }
        }
        // col direction: min over this wave's 32 rows (m ascending within lane)
        {
            float cv = 3.4e38f; unsigned ci = 0u;
            #pragma unroll
            for (int r = 0; r < 16; ++r) {
                int mloc = w * 32 + (r & 3) + 8 * (r >> 2) + 4 * half;
                float val = s_nA[mloc] - 2.0f * acc[r];
                if (val < cv) { cv = val; ci = (unsigned)(m0 + mloc); }
            }
            float    ov = __shfl_xor(cv, 32);
            unsigned oi = __shfl_xor(ci, 32);
            if (ov < cv || (ov == cv && oi < ci)) { cv = ov; ci = oi; }
            if (half == 0) { s_cv[w][nt * 32 + cl] = cv; s_ci[w][nt * 32 + cl] = ci; }
        }
        __syncthreads();            // buf consumed by all; drains in-flight stage
        if (nt < 2) STAGE(buf, nt + 2);   // refill freed buffer, 2-phase cover
    }
#undef STAGE

    // row-min shuffle-reduce over the 32 cols (cl), lowest-index tie-break
    #pragma unroll
    for (int off = 1; off <= 16; off <<= 1) {
        #pragma unroll
        for (int r = 0; r < 16; ++r) {
            float    ov = __shfl_xor(rv[r], off);
            unsigned oi = __shfl_xor(ri[r], off);
            if (ov < rv[r] || (ov == rv[r] && oi < ri[r])) { rv[r] = ov; ri[r] = oi; }
        }
    }
    if (cl == 0) {
        #pragma unroll
        for (int r = 0; r < 16; ++r) {
            int mloc = w * 32 + (r & 3) + 8 * (r >> 2) + 4 * half;
            g_rval[b][cs][m0 + mloc] = rv[r];
            g_ridx[b][cs][m0 + mloc] = ri[r];
        }
    }
    // cross-wave col reduce (s_cv complete: synced at end of nt=3)
    if (t < 128) {
        float v = s_cv[0][t]; unsigned id = s_ci[0][t];
        #pragma unroll
        for (int wv = 1; wv < 4; ++wv) {
            float ov = s_cv[wv][t]; unsigned oi = s_ci[wv][t];
            if (ov < v || (ov == v && oi < id)) { v = ov; id = oi; }
        }
        g_cval[b][rt][n0 + t] = v;
        g_cidx[b][rt][n0 + t] = id;
    }
}

// ---------------------------------------------------------------------------
// Combine partials: gid<16384 row direction (idx1, over 8 cs), else col (idx2,
// over 8 rt). Explicit value+index tie-break keeps lowest index.
__global__ __launch_bounds__(256)
void minreduce_kernel()
{
    int gid = blockIdx.x * 256 + threadIdx.x;   // 0..32767
    if (gid < 16384) {
        int b = gid >> 10, m = gid & 1023;
        float v = g_rval[b][0][m]; unsigned id = g_ridx[b][0][m];
        #pragma unroll
        for (int cs = 1; cs < 8; ++cs) {
            float ov = g_rval[b][cs][m]; unsigned oi = g_ridx[b][cs][m];
            if (ov < v || (ov == v && oi < id)) { v = ov; id = oi; }
        }
        g_idx[0][b * NM + m] = id;
    } else {
        int g2 = gid - 16384;
        int b = g2 >> 10, n = g2 & 1023;
        float v = g_cval[b][0][n]; unsigned id = g_cidx[b][0][n];
        #pragma unroll
        for (int rt = 1; rt < 8; ++rt) {
            float ov = g_cval[b][rt][n]; unsigned oi = g_cidx[b][rt][n];
            if (ov < v || (ov == v && oi < id)) { v = ov; id = oi; }
        }
        g_idx[1][b * NM + n] = id;
    }
}

// ---------------------------------------------------------------------------
// Per-position losses. One block per position m. Mats: 0=m1, 1=nn1, 2=m2, 3=nn2.
// Rows reconstructed from bf16 hi+lo (error ~1e-5 rel, thresholds are 0.685).
__global__ __launch_bounds__(256)
void loss_kernel()
{
    __shared__ float Z[4 * 16 * ZS];     // 33 KB, rows 16B-aligned
    __shared__ float red[12];
    const int m = blockIdx.x;
    const int t = threadIdx.x;
    const int o  = t & 15;               // k-octet
    const int bb = t >> 4;               // batch

    const unsigned r1 = g_idx[0][bb * NM + m];
    const unsigned r2 = g_idx[1][bb * NM + m];
    const unsigned rows[4] = { (unsigned)m, r1, (unsigned)m, r2 };
    #pragma unroll
    for (int mat = 0; mat < 4; ++mat) {
        const unsigned short* SH = (mat == 0 || mat == 3) ? g_FH[0] : g_FH[1];
        const unsigned short* SL = (mat == 0 || mat == 3) ? g_FL[0] : g_FL[1];
        const unsigned row = rows[mat];
        size_t base = (((size_t)(bb * 32 + (row >> 5)) * 8 + (o >> 1)) * 64
                       + (o & 1) * 32 + (row & 31)) * 8;
        short8v hv = *(const short8v*)(SH + base);
        short8v lv = *(const short8v*)(SL + base);
        #pragma unroll
        for (int e = 0; e < 8; ++e) {
            float v = __uint_as_float(((unsigned)(unsigned short)hv[e]) << 16)
                    + __uint_as_float(((unsigned)(unsigned short)lv[e]) << 16);
            Z[mat * 16 * ZS + bb * ZS + o * 8 + e] = v;
        }
    }
    __syncthreads();

    // repr loss partial (uncentered)
    float racc = 0.f;
    #pragma unroll
    for (int i = 0; i < 8; ++i) {
        int idx = t + i * 256;
        int b = idx >> 7, c = idx & 127;
        float d0 = Z[0 * 16 * ZS + b * ZS + c] - Z[1 * 16 * ZS + b * ZS + c];
        float d1 = Z[2 * 16 * ZS + b * ZS + c] - Z[3 * 16 * ZS + b * ZS + c];
        racc += d0 * d0 + d1 * d1;
    }
    __syncthreads();                     // repr reads before centering writes

    // column stats: center in place, variance, std-loss, diag² accumulation
    float sacc = 0.f, qdacc = 0.f;
    #pragma unroll
    for (int pass = 0; pass < 2; ++pass) {
        int mat = (t >> 7) + pass * 2;
        int c   = t & 127;
        float* Zm = &Z[mat * 16 * ZS];
        float mu = 0.f;
        #pragma unroll
        for (int b = 0; b < 16; ++b) mu += Zm[b * ZS + c];
        mu *= 0.0625f;
        float d = 0.f;
        #pragma unroll
        for (int b = 0; b < 16; ++b) {
            float v = Zm[b * ZS + c] - mu;
            Zm[b * ZS + c] = v;
            d += v * v;
        }
        float stdv = sqrtf(d * (1.0f / 15.0f) + 1e-4f);
        sacc  += fmaxf(1.0f - stdv, 0.f);
        qdacc += d * d;
    }
    __syncthreads();

    // 16x16 Gram per matrix: ||X^T X||_F^2 == ||X X^T||_F^2 ; float4 LDS reads
    float qaacc = 0.f;
    const int gi = t >> 4, gj = t & 15;
    #pragma unroll
    for (int mat = 0; mat < 4; ++mat) {
        const float* Zi = &Z[mat * 16 * ZS + gi * ZS];
        const float* Zj = &Z[mat * 16 * ZS + gj * ZS];
        float g = 0.f;
        #pragma unroll 8
        for (int c = 0; c < NC; c += 4) {
            float4 a  = *reinterpret_cast<const float4*>(&Zi[c]);
            float4 bv = *reinterpret_cast<const float4*>(&Zj[c]);
            g += a.x * bv.x + a.y * bv.y + a.z * bv.z + a.w * bv.w;
        }
        qaacc += g * g;
    }

    // block-reduce the three partials
    float v0 = racc, v1 = sacc, v2 = qaacc - qdacc;
    #pragma unroll
    for (int off = 32; off >= 1; off >>= 1) {
        v0 += __shfl_xor(v0, off);
        v1 += __shfl_xor(v1, off);
        v2 += __shfl_xor(v2, off);
    }
    const int w = t >> 6;
    if ((t & 63) == 0) { red[w] = v0; red[4 + w] = v1; red[8 + w] = v2; }
    __syncthreads();
    if (t == 0) {
        g_part[0][m] = red[0] + red[1] + red[2] + red[3];
        g_part[1][m] = red[4] + red[5] + red[6] + red[7];
        g_part[2][m] = red[8] + red[9] + red[10] + red[11];
    }
}

// ---------------------------------------------------------------------------
__global__ __launch_bounds__(256)
void final_kernel(float* __restrict__ out)
{
    const int t = threadIdx.x;
    float r = 0.f, s = 0.f, q = 0.f;
    for (int i = t; i < NM; i += 256) {
        r += g_part[0][i];
        s += g_part[1][i];
        q += g_part[2][i];
    }
    __shared__ float red[12];
    #pragma unroll
    for (int off = 32; off >= 1; off >>= 1) {
        r += __shfl_xor(r, off);
        s += __shfl_xor(s, off);
        q += __shfl_xor(q, off);
    }
    const int w = t >> 6;
    if ((t & 63) == 0) { red[w] = r; red[4 + w] = s; red[8 + w] = q; }
    __syncthreads();
    if (t == 0) {
        r = red[0] + red[1] + red[2] + red[3];
        s = red[4] + red[5] + red[6] + red[7];
        q = red[8] + red[9] + red[10] + red[11];
        out[0] = r * (25.0f / 4194304.0f);
        out[1] = s * (25.0f / 524288.0f);
        out[2] = q * (1.0f / (225.0f * 1024.0f * 512.0f));
    }
}

// ---------------------------------------------------------------------------
extern "C" void kernel_launch(void* const* d_in, const int* in_sizes, int n_in,
                              void* d_out, int out_size, void* d_ws, size_t ws_size,
                              hipStream_t stream)
{
    const float* e1 = (const float*)d_in[0];
    const float* e2 = (const float*)d_in[1];
    float* out = (float*)d_out;

    transpose_kernel<<<dim3(16, 2, 32), 256, 0, stream>>>(e1, e2);
    norm_kernel<<<128, 256, 0, stream>>>(e1, e2);
    argmin6_kernel<<<1024, 256, 0, stream>>>();
    minreduce_kernel<<<128, 256, 0, stream>>>();
    loss_kernel<<<1024, 256, 0, stream>>>();
    final_kernel<<<1, 256, 0, stream>>>(out);
}

// Round 7
// 88.616 us; speedup vs baseline: 1.5121x; 1.1295x over previous
//
#include <hip/hip_runtime.h>
#include <hip/hip_bf16.h>
#include <math.h>

// Problem constants: B=16, C=128, M=H*W=1024.
#define NB 16
#define NC 128
#define NM 1024
#define ZS 132   // loss LDS row stride (16B-aligned, bank-shifted)

typedef __attribute__((ext_vector_type(8))) short  short8v;   // 8 bf16 = 4 VGPR
typedef __attribute__((ext_vector_type(16))) float floatx16;  // MFMA 32x32 acc

// Persistent device scratch (fully rewritten every call -> deterministic).
// Fragment-linear bf16 hi/lo: chunk = (b*32 + row/32)*8 + k/16 is a 1KB wave
// fragment; within it lane = ((k>>3)&1)*32 | (row&31) holds 8 consecutive k.
__device__ unsigned short g_FH[2][NB * NM * NC]; // bf16 hi
__device__ unsigned short g_FL[2][NB * NM * NC]; // bf16 lo (loss reconstruct only)
__device__ float    g_norm[2][NB * NM];       // ||token||^2 per matrix (exact fp32)
__device__ float    g_part[3][NM];            // per-position partials: R, S, Qraw
__device__ float    g_rval[NB][8][NM];        // row-min partials over 8 col-splits
__device__ unsigned g_ridx[NB][8][NM];
__device__ float    g_cval[NB][8][NM];        // col-min partials over 8 row-tiles
__device__ unsigned g_cidx[NB][8][NM];

// ---------------------------------------------------------------------------
// Transpose E[b][c][p] (c-major) -> bf16 hi/lo fragment-linear, coalesced 16B
// stores (one 8-k octet per thread-task).
__global__ __launch_bounds__(256)
void transpose_kernel(const float* __restrict__ e1, const float* __restrict__ e2)
{
    __shared__ float tile[64][65];
    const int z   = blockIdx.z;
    const int b   = z >> 1;
    const int mat = z & 1;
    const float* src = mat ? e2 : e1;
    const int p0 = blockIdx.x * 64;
    const int c0 = blockIdx.y * 64;
    const int t  = threadIdx.x;
    const int tj = t & 63;
    const int ti = t >> 6;               // 0..3
    const float* sb = src + (size_t)b * NC * NM;
    #pragma unroll
    for (int i = 0; i < 16; ++i) {
        int c = i * 4 + ti;
        tile[c][tj] = sb[(size_t)(c0 + c) * NM + p0 + tj];
    }
    __syncthreads();
    unsigned short* fh = g_FH[mat];
    unsigned short* fl = g_FL[mat];
    #pragma unroll
    for (int it = 0; it < 2; ++it) {
        const int p  = t & 63;
        const int ko = (t >> 6) + it * 4;      // 0..7 k-octet within c-tile
        short8v hv, lv;
        #pragma unroll
        for (int e = 0; e < 8; ++e) {
            float v = tile[ko * 8 + e][p];
            unsigned xb = __float_as_uint(v);
            unsigned hr = (xb + 0x7FFFu + ((xb >> 16) & 1u)) >> 16;
            float h = __uint_as_float(hr << 16);
            float l = v - h;
            unsigned lb = __float_as_uint(l);
            unsigned lr = (lb + 0x7FFFu + ((lb >> 16) & 1u)) >> 16;
            hv[e] = (short)hr;
            lv[e] = (short)lr;
        }
        const int row = p0 + p, k = c0 + ko * 8;
        size_t base = (((size_t)(b * 32 + (row >> 5)) * 8 + (k >> 4)) * 64
                       + ((k >> 3) & 1) * 32 + (row & 31)) * 8;
        *reinterpret_cast<short8v*>(fh + base) = hv;
        *reinterpret_cast<short8v*>(fl + base) = lv;
    }
}

// ---------------------------------------------------------------------------
// Token norms directly from the c-major layout (coalesced over p), exact fp32.
__global__ __launch_bounds__(256)
void norm_kernel(const float* __restrict__ e1, const float* __restrict__ e2)
{
    const int z   = blockIdx.x;
    const int mat = z >> 6;
    const int b   = (z >> 2) & 15;
    const int pc  = z & 3;
    const float* src = mat ? e2 : e1;
    const int p = pc * 256 + threadIdx.x;
    const float* sb = src + (size_t)b * NC * NM + p;
    float s = 0.f;
    #pragma unroll 4
    for (int c = 0; c < NC; ++c) {
        float v = sb[(size_t)c * NM];
        s += v * v;
    }
    g_norm[mat][b * NM + p] = s;
}

// ---------------------------------------------------------------------------
// 1-term bf16 MFMA distance-argmin. dot(hi,hi) has RMS error ~0.02 on squared
// distances with O(1..10) argmin gaps -> flips only on near-ties, each worth
// <1e-3 on outputs (threshold 0.685). Block = 128m x 128n, 4 waves, monolithic
// 32KB B-stage via global_load_lds, A hi-frags in 32 VGPRs, one barrier,
// 32 MFMAs. LDS 38KB -> 4 blocks/CU. XCD-chunked swizzle: each XCD owns 2
// whole batches -> panels L2-resident per XCD.
__global__ __launch_bounds__(256, 4)
void argmin7_kernel()
{
    __shared__ unsigned short lBH[4 * 8 * 512];   // 32 KB (hi only)
    __shared__ float    s_nA[128], s_nB[128];
    __shared__ float    s_cv[4][128];
    __shared__ unsigned s_ci[4][128];

    const int raw  = blockIdx.x;
    const int lblk = (raw & 7) * 128 + (raw >> 3);   // bijective XCD chunking
    const int b  = lblk >> 6;
    const int rt = (lblk >> 3) & 7;
    const int cs = lblk & 7;
    const int m0 = rt << 7;
    const int n0 = cs << 7;
    const int t  = threadIdx.x;
    const int w  = t >> 6;
    const int lane = t & 63;
    const int cl   = lane & 31;
    const int half = lane >> 5;

    // ---- stage B hi panel (4 x 32-col tiles, contiguous 32KB), linear dest
    const size_t bbase = ((size_t)(b * 32 + (n0 >> 5)) * 8) * 512;  // ushort
    #pragma unroll
    for (int i = 0; i < 8; ++i) {
        int f = i * 256 + t;                 // 0..2047 16B chunks
        __builtin_amdgcn_global_load_lds(
            (__attribute__((address_space(1))) void*)(g_FH[1] + bbase + (size_t)f * 8),
            (__attribute__((address_space(3))) void*)&lBH[f * 8], 16, 0, 0);
    }
    if (t < 128) {
        s_nA[t] = g_norm[0][b * NM + m0 + t];
        s_nB[t] = g_norm[1][b * NM + n0 + t];
    }

    // ---- A hi-fragments straight to registers (coalesced 1KB wave reads)
    const size_t abase = (size_t)((b * 32 + (m0 >> 5) + w) * 8) * 64 + lane;
    const short8v* FAH = (const short8v*)g_FH[0];
    short8v aH[8];
    #pragma unroll
    for (int s = 0; s < 8; ++s) aH[s] = FAH[abase + s * 64];

    float rv[16]; unsigned ri[16];
    #pragma unroll
    for (int r = 0; r < 16; ++r) { rv[r] = 3.4e38f; ri[r] = 0u; }

    __syncthreads();   // drains staging + A loads

    #pragma unroll
    for (int nt = 0; nt < 4; ++nt) {
        floatx16 acc = {};
        #pragma unroll
        for (int s = 0; s < 8; ++s) {
            short8v bh = *(const short8v*)&lBH[(nt * 8 + s) * 512 + lane * 8];
            acc = __builtin_amdgcn_mfma_f32_32x32x16_bf16(aH[s], bh, acc, 0, 0, 0);
        }
        // C/D map: col = cl (+32*nt), row(reg r) = (r&3)+8*(r>>2)+4*half (+32*w)
        // row direction: n ascending within lane -> strict < keeps lowest n
        {
            const float nv = s_nB[nt * 32 + cl];
            const unsigned n = (unsigned)(n0 + nt * 32 + cl);
            #pragma unroll
            for (int r = 0; r < 16; ++r) {
                float val = nv - 2.0f * acc[r];
                if (val < rv[r]) { rv[r] = val; ri[r] = n; }
            }
        }
        // col direction: min over this wave's 32 rows (m ascending within lane)
        {
            float cv = 3.4e38f; unsigned ci = 0u;
            #pragma unroll
            for (int r = 0; r < 16; ++r) {
                int mloc = w * 32 + (r & 3) + 8 * (r >> 2) + 4 * half;
                float val = s_nA[mloc] - 2.0f * acc[r];
                if (val < cv) { cv = val; ci = (unsigned)(m0 + mloc); }
            }
            float    ov = __shfl_xor(cv, 32);
            unsigned oi = __shfl_xor(ci, 32);
            if (ov < cv || (ov == cv && oi < ci)) { cv = ov; ci = oi; }
            if (half == 0) { s_cv[w][nt * 32 + cl] = cv; s_ci[w][nt * 32 + cl] = ci; }
        }
        // no barrier: lBH is read-only now, s_cv slots are disjoint per (w,nt)
    }

    // row-min shuffle-reduce over the 32 cols (cl), lowest-index tie-break
    #pragma unroll
    for (int off = 1; off <= 16; off <<= 1) {
        #pragma unroll
        for (int r = 0; r < 16; ++r) {
            float    ov = __shfl_xor(rv[r], off);
            unsigned oi = __shfl_xor(ri[r], off);
            if (ov < rv[r] || (ov == rv[r] && oi < ri[r])) { rv[r] = ov; ri[r] = oi; }
        }
    }
    if (cl == 0) {
        #pragma unroll
        for (int r = 0; r < 16; ++r) {
            int mloc = w * 32 + (r & 3) + 8 * (r >> 2) + 4 * half;
            g_rval[b][cs][m0 + mloc] = rv[r];
            g_ridx[b][cs][m0 + mloc] = ri[r];
        }
    }
    __syncthreads();   // s_cv complete across waves
    if (t < 128) {
        float v = s_cv[0][t]; unsigned id = s_ci[0][t];
        #pragma unroll
        for (int wv = 1; wv < 4; ++wv) {
            float ov = s_cv[wv][t]; unsigned oi = s_ci[wv][t];
            if (ov < v || (ov == v && oi < id)) { v = ov; id = oi; }
        }
        g_cval[b][rt][n0 + t] = v;
        g_cidx[b][rt][n0 + t] = id;
    }
}

// ---------------------------------------------------------------------------
// Per-position losses with fused argmin-combine. One block per position m.
// Mats: 0=m1, 1=nn1, 2=m2, 3=nn2; values reconstructed from bf16 hi+lo.
__global__ __launch_bounds__(256)
void loss_kernel()
{
    __shared__ float Z[4 * 16 * ZS];     // 33 KB, rows 16B-aligned
    __shared__ float sP[4][16][17];      // Gram half-partials (padded)
    __shared__ unsigned s_rr[2][16];
    __shared__ float red[12];
    const int m = blockIdx.x;
    const int t = threadIdx.x;

    // fused min-combine: idx1 (over 8 cs) / idx2 (over 8 rt) per batch
    if (t < 32) {
        const int dir = t >> 4, b = t & 15;
        if (dir == 0) {
            float v = g_rval[b][0][m]; unsigned id = g_ridx[b][0][m];
            #pragma unroll
            for (int cs = 1; cs < 8; ++cs) {
                float ov = g_rval[b][cs][m]; unsigned oi = g_ridx[b][cs][m];
                if (ov < v || (ov == v && oi < id)) { v = ov; id = oi; }
            }
            s_rr[0][b] = id;
        } else {
            float v = g_cval[b][0][m]; unsigned id = g_cidx[b][0][m];
            #pragma unroll
            for (int rt = 1; rt < 8; ++rt) {
                float ov = g_cval[b][rt][m]; unsigned oi = g_cidx[b][rt][m];
                if (ov < v || (ov == v && oi < id)) { v = ov; id = oi; }
            }
            s_rr[1][b] = id;
        }
    }
    __syncthreads();

    const int o  = t & 15;               // k-octet
    const int bb = t >> 4;               // batch
    const unsigned rows[4] = { (unsigned)m, s_rr[0][bb], (unsigned)m, s_rr[1][bb] };
    #pragma unroll
    for (int mat = 0; mat < 4; ++mat) {
        const unsigned short* SH = (mat == 0 || mat == 3) ? g_FH[0] : g_FH[1];
        const unsigned short* SL = (mat == 0 || mat == 3) ? g_FL[0] : g_FL[1];
        const unsigned row = rows[mat];
        size_t base = (((size_t)(bb * 32 + (row >> 5)) * 8 + (o >> 1)) * 64
                       + (o & 1) * 32 + (row & 31)) * 8;
        short8v hv = *(const short8v*)(SH + base);
        short8v lv = *(const short8v*)(SL + base);
        #pragma unroll
        for (int e = 0; e < 8; ++e) {
            float v = __uint_as_float(((unsigned)(unsigned short)hv[e]) << 16)
                    + __uint_as_float(((unsigned)(unsigned short)lv[e]) << 16);
            Z[mat * 16 * ZS + bb * ZS + o * 8 + e] = v;
        }
    }
    __syncthreads();

    // repr loss partial (uncentered)
    float racc = 0.f;
    #pragma unroll
    for (int i = 0; i < 8; ++i) {
        int idx = t + i * 256;
        int b = idx >> 7, c = idx & 127;
        float d0 = Z[0 * 16 * ZS + b * ZS + c] - Z[1 * 16 * ZS + b * ZS + c];
        float d1 = Z[2 * 16 * ZS + b * ZS + c] - Z[3 * 16 * ZS + b * ZS + c];
        racc += d0 * d0 + d1 * d1;
    }
    __syncthreads();                     // repr reads before centering writes

    // column stats: center in place, variance, std-loss, diag² accumulation
    float sacc = 0.f, qdacc = 0.f;
    #pragma unroll
    for (int pass = 0; pass < 2; ++pass) {
        int mat = (t >> 7) + pass * 2;
        int c   = t & 127;
        float* Zm = &Z[mat * 16 * ZS];
        float mu = 0.f;
        #pragma unroll
        for (int b = 0; b < 16; ++b) mu += Zm[b * ZS + c];
        mu *= 0.0625f;
        float d = 0.f;
        #pragma unroll
        for (int b = 0; b < 16; ++b) {
            float v = Zm[b * ZS + c] - mu;
            Zm[b * ZS + c] = v;
            d += v * v;
        }
        float stdv = sqrtf(d * (1.0f / 15.0f) + 1e-4f);
        sacc  += fmaxf(1.0f - stdv, 0.f);
        qdacc += d * d;
    }
    __syncthreads();

    // 16x16 Gram per matrix, symmetric c-split: thread (gi,gj) covers
    // c in [0,64) if gi<=gj else [64,128); diag covers all. G = P + P^T.
    const int gi = t >> 4, gj = t & 15;
    const int c0 = (gi <= gj) ? 0 : 64;
    const int c1 = (gi == gj) ? 128 : c0 + 64;
    float P[4];
    #pragma unroll
    for (int mat = 0; mat < 4; ++mat) {
        const float* Zi = &Z[mat * 16 * ZS + gi * ZS];
        const float* Zj = &Z[mat * 16 * ZS + gj * ZS];
        float g = 0.f;
        #pragma unroll 4
        for (int c = c0; c < c1; c += 4) {
            float4 a  = *reinterpret_cast<const float4*>(&Zi[c]);
            float4 bv = *reinterpret_cast<const float4*>(&Zj[c]);
            g += a.x * bv.x + a.y * bv.y + a.z * bv.z + a.w * bv.w;
        }
        P[mat] = g;
        sP[mat][gi][gj] = g;
    }
    __syncthreads();
    float qaacc = 0.f;
    #pragma unroll
    for (int mat = 0; mat < 4; ++mat) {
        float G = (gi == gj) ? P[mat] : (P[mat] + sP[mat][gj][gi]);
        qaacc += G * G;
    }

    // block-reduce the three partials
    float v0 = racc, v1 = sacc, v2 = qaacc - qdacc;
    #pragma unroll
    for (int off = 32; off >= 1; off >>= 1) {
        v0 += __shfl_xor(v0, off);
        v1 += __shfl_xor(v1, off);
        v2 += __shfl_xor(v2, off);
    }
    const int w = t >> 6;
    if ((t & 63) == 0) { red[w] = v0; red[4 + w] = v1; red[8 + w] = v2; }
    __syncthreads();
    if (t == 0) {
        g_part[0][m] = red[0] + red[1] + red[2] + red[3];
        g_part[1][m] = red[4] + red[5] + red[6] + red[7];
        g_part[2][m] = red[8] + red[9] + red[10] + red[11];
    }
}

// ---------------------------------------------------------------------------
__global__ __launch_bounds__(256)
void final_kernel(float* __restrict__ out)
{
    const int t = threadIdx.x;
    float r = 0.f, s = 0.f, q = 0.f;
    for (int i = t; i < NM; i += 256) {
        r += g_part[0][i];
        s += g_part[1][i];
        q += g_part[2][i];
    }
    __shared__ float red[12];
    #pragma unroll
    for (int off = 32; off >= 1; off >>= 1) {
        r += __shfl_xor(r, off);
        s += __shfl_xor(s, off);
        q += __shfl_xor(q, off);
    }
    const int w = t >> 6;
    if ((t & 63) == 0) { red[w] = r; red[4 + w] = s; red[8 + w] = q; }
    __syncthreads();
    if (t == 0) {
        r = red[0] + red[1] + red[2] + red[3];
        s = red[4] + red[5] + red[6] + red[7];
        q = red[8] + red[9] + red[10] + red[11];
        out[0] = r * (25.0f / 4194304.0f);
        out[1] = s * (25.0f / 524288.0f);
        out[2] = q * (1.0f / (225.0f * 1024.0f * 512.0f));
    }
}

// ---------------------------------------------------------------------------
extern "C" void kernel_launch(void* const* d_in, const int* in_sizes, int n_in,
                              void* d_out, int out_size, void* d_ws, size_t ws_size,
                              hipStream_t stream)
{
    const float* e1 = (const float*)d_in[0];
    const float* e2 = (const float*)d_in[1];
    float* out = (float*)d_out;

    transpose_kernel<<<dim3(16, 2, 32), 256, 0, stream>>>(e1, e2);
    norm_kernel<<<128, 256, 0, stream>>>(e1, e2);
    argmin7_kernel<<<1024, 256, 0, stream>>>();
    loss_kernel<<<1024, 256, 0, stream>>>();
    final_kernel<<<1, 256, 0, stream>>>(out);
}

// Round 8
// 56.586 us; speedup vs baseline: 2.3681x; 1.5660x over previous
//
#include <hip/hip_runtime.h>
#include <hip/hip_bf16.h>
#include <math.h>

// Problem constants: B=16, C=128, M=H*W=1024.
#define NB 16
#define NC 128
#define NM 1024
#define ZS 132   // loss LDS row stride (16B-aligned, bank-shifted)

typedef __attribute__((ext_vector_type(8))) short  short8v;   // 8 bf16 = 4 VGPR
typedef __attribute__((ext_vector_type(16))) float floatx16;  // MFMA 32x32 acc

// Persistent device scratch (fully rewritten every call -> deterministic).
// g_FH: fragment-linear bf16 hi for the MFMA argmin. chunk = (b*32+row/32)*8
// + k/16 is a 1KB wave fragment; lane = ((k>>3)&1)*32 | (row&31), 8 k/lane.
// g_T: token-major fp32 (contiguous 512B rows) for the loss gather.
__device__ unsigned short g_FH[2][NB * NM * NC];
__device__ float    g_T[2][NB * NM * NC];
__device__ float    g_npart[2][2][NB * NM];   // per-position norm partials (c-halves)
__device__ float    g_part[3][NM];            // per-position partials: R, S, Qraw
__device__ float    g_rval[NB][8][NM];        // row-min partials over 8 col-splits
__device__ unsigned g_ridx[NB][8][NM];
__device__ float    g_cval[NB][8][NM];        // col-min partials over 8 row-tiles
__device__ unsigned g_cidx[NB][8][NM];

// ---------------------------------------------------------------------------
// Transpose E[b][c][p] (c-major) -> g_T fp32 token-major + g_FH bf16-hi
// fragment-linear + per-position norm partials. All stores coalesced.
__global__ __launch_bounds__(256)
void transpose_kernel(const float* __restrict__ e1, const float* __restrict__ e2)
{
    __shared__ float tile[64][65];
    __shared__ float s_np[4][64];
    const int z   = blockIdx.z;
    const int b   = z >> 1;
    const int mat = z & 1;
    const float* src = mat ? e2 : e1;
    const int p0 = blockIdx.x * 64;
    const int c0 = blockIdx.y * 64;
    const int t  = threadIdx.x;
    const int tj = t & 63;
    const int ti = t >> 6;               // 0..3
    const float* sb = src + (size_t)b * NC * NM;
    #pragma unroll
    for (int i = 0; i < 16; ++i) {
        int c = i * 4 + ti;
        tile[c][tj] = sb[(size_t)(c0 + c) * NM + p0 + tj];
    }
    __syncthreads();

    // fp32 token-major rows (contiguous in c)
    float* db = g_T[mat] + (size_t)b * NM * NC;
    #pragma unroll
    for (int i = 0; i < 16; ++i) {
        int p = i * 4 + ti;
        db[(size_t)(p0 + p) * NC + c0 + tj] = tile[tj][p];
    }

    // bf16-hi fragment-linear + norm partials
    unsigned short* fh = g_FH[mat];
    float np = 0.f;
    #pragma unroll
    for (int it = 0; it < 2; ++it) {
        const int p  = t & 63;
        const int ko = (t >> 6) + it * 4;      // 0..7 k-octet within c-tile
        short8v hv;
        #pragma unroll
        for (int e = 0; e < 8; ++e) {
            float v = tile[ko * 8 + e][p];
            np += v * v;
            unsigned xb = __float_as_uint(v);
            unsigned hr = (xb + 0x7FFFu + ((xb >> 16) & 1u)) >> 16;
            hv[e] = (short)hr;
        }
        const int row = p0 + p, k = c0 + ko * 8;
        size_t base = (((size_t)(b * 32 + (row >> 5)) * 8 + (k >> 4)) * 64
                       + ((k >> 3) & 1) * 32 + (row & 31)) * 8;
        *reinterpret_cast<short8v*>(fh + base) = hv;
    }
    s_np[ti][tj] = np;
    __syncthreads();
    if (t < 64)
        g_npart[mat][blockIdx.y][b * NM + p0 + t]
            = s_np[0][t] + s_np[1][t] + s_np[2][t] + s_np[3][t];
}

// ---------------------------------------------------------------------------
// 1-term bf16 MFMA distance-argmin (validated round 7: absmax stayed 0.0).
// Block = 128m x 128n, 4 waves, monolithic 32KB B-stage via global_load_lds,
// A hi-frags in 32 VGPRs, one barrier, 32 MFMAs. XCD-chunked swizzle: each
// XCD owns 2 whole batches -> panels L2-resident per XCD.
__global__ __launch_bounds__(256, 4)
void argmin7_kernel()
{
    __shared__ unsigned short lBH[4 * 8 * 512];   // 32 KB (hi only)
    __shared__ float    s_nA[128], s_nB[128];
    __shared__ float    s_cv[4][128];
    __shared__ unsigned s_ci[4][128];

    const int raw  = blockIdx.x;
    const int lblk = (raw & 7) * 128 + (raw >> 3);   // bijective XCD chunking
    const int b  = lblk >> 6;
    const int rt = (lblk >> 3) & 7;
    const int cs = lblk & 7;
    const int m0 = rt << 7;
    const int n0 = cs << 7;
    const int t  = threadIdx.x;
    const int w  = t >> 6;
    const int lane = t & 63;
    const int cl   = lane & 31;
    const int half = lane >> 5;

    // ---- stage B hi panel (4 x 32-col tiles, contiguous 32KB), linear dest
    const size_t bbase = ((size_t)(b * 32 + (n0 >> 5)) * 8) * 512;  // ushort
    #pragma unroll
    for (int i = 0; i < 8; ++i) {
        int f = i * 256 + t;                 // 0..2047 16B chunks
        __builtin_amdgcn_global_load_lds(
            (__attribute__((address_space(1))) void*)(g_FH[1] + bbase + (size_t)f * 8),
            (__attribute__((address_space(3))) void*)&lBH[f * 8], 16, 0, 0);
    }
    if (t < 128) {
        s_nA[t] = g_npart[0][0][b * NM + m0 + t] + g_npart[0][1][b * NM + m0 + t];
        s_nB[t] = g_npart[1][0][b * NM + n0 + t] + g_npart[1][1][b * NM + n0 + t];
    }

    // ---- A hi-fragments straight to registers (coalesced 1KB wave reads)
    const size_t abase = (size_t)((b * 32 + (m0 >> 5) + w) * 8) * 64 + lane;
    const short8v* FAH = (const short8v*)g_FH[0];
    short8v aH[8];
    #pragma unroll
    for (int s = 0; s < 8; ++s) aH[s] = FAH[abase + s * 64];

    float rv[16]; unsigned ri[16];
    #pragma unroll
    for (int r = 0; r < 16; ++r) { rv[r] = 3.4e38f; ri[r] = 0u; }

    __syncthreads();   // drains staging + A loads

    #pragma unroll
    for (int nt = 0; nt < 4; ++nt) {
        floatx16 acc = {};
        #pragma unroll
        for (int s = 0; s < 8; ++s) {
            short8v bh = *(const short8v*)&lBH[(nt * 8 + s) * 512 + lane * 8];
            acc = __builtin_amdgcn_mfma_f32_32x32x16_bf16(aH[s], bh, acc, 0, 0, 0);
        }
        // C/D map: col = cl (+32*nt), row(reg r) = (r&3)+8*(r>>2)+4*half (+32*w)
        // row direction: n ascending within lane -> strict < keeps lowest n
        {
            const float nv = s_nB[nt * 32 + cl];
            const unsigned n = (unsigned)(n0 + nt * 32 + cl);
            #pragma unroll
            for (int r = 0; r < 16; ++r) {
                float val = nv - 2.0f * acc[r];
                if (val < rv[r]) { rv[r] = val; ri[r] = n; }
            }
        }
        // col direction: min over this wave's 32 rows (m ascending within lane)
        {
            float cv = 3.4e38f; unsigned ci = 0u;
            #pragma unroll
            for (int r = 0; r < 16; ++r) {
                int mloc = w * 32 + (r & 3) + 8 * (r >> 2) + 4 * half;
                float val = s_nA[mloc] - 2.0f * acc[r];
                if (val < cv) { cv = val; ci = (unsigned)(m0 + mloc); }
            }
            float    ov = __shfl_xor(cv, 32);
            unsigned oi = __shfl_xor(ci, 32);
            if (ov < cv || (ov == cv && oi < ci)) { cv = ov; ci = oi; }
            if (half == 0) { s_cv[w][nt * 32 + cl] = cv; s_ci[w][nt * 32 + cl] = ci; }
        }
        // no barrier: lBH is read-only now, s_cv slots are disjoint per (w,nt)
    }

    // row-min shuffle-reduce over the 32 cols (cl), lowest-index tie-break
    #pragma unroll
    for (int off = 1; off <= 16; off <<= 1) {
        #pragma unroll
        for (int r = 0; r < 16; ++r) {
            float    ov = __shfl_xor(rv[r], off);
            unsigned oi = __shfl_xor(ri[r], off);
            if (ov < rv[r] || (ov == rv[r] && oi < ri[r])) { rv[r] = ov; ri[r] = oi; }
        }
    }
    if (cl == 0) {
        #pragma unroll
        for (int r = 0; r < 16; ++r) {
            int mloc = w * 32 + (r & 3) + 8 * (r >> 2) + 4 * half;
            g_rval[b][cs][m0 + mloc] = rv[r];
            g_ridx[b][cs][m0 + mloc] = ri[r];
        }
    }
    __syncthreads();   // s_cv complete across waves
    if (t < 128) {
        float v = s_cv[0][t]; unsigned id = s_ci[0][t];
        #pragma unroll
        for (int wv = 1; wv < 4; ++wv) {
            float ov = s_cv[wv][t]; unsigned oi = s_ci[wv][t];
            if (ov < v || (ov == v && oi < id)) { v = ov; id = oi; }
        }
        g_cval[b][rt][n0 + t] = v;
        g_cidx[b][rt][n0 + t] = id;
    }
}

// ---------------------------------------------------------------------------
// Per-position losses with fused argmin-combine. One block per position m.
// Mats: 0=m1, 1=nn1, 2=m2, 3=nn2; fp32 rows gathered from token-major g_T
// (contiguous 512B per row -> zero over-fetch).
__global__ __launch_bounds__(256)
void loss_kernel()
{
    __shared__ float Z[4 * 16 * ZS];     // 33 KB, rows 16B-aligned
    __shared__ float sP[4][16][17];      // Gram half-partials (padded)
    __shared__ unsigned s_rr[2][16];
    __shared__ float red[12];
    const int m = blockIdx.x;
    const int t = threadIdx.x;

    // parallel min-combine: 256 threads = dir(2) x b(16) x split(8)
    {
        const int dir = t >> 7;
        const int b   = (t >> 3) & 15;
        const int spl = t & 7;
        float v; unsigned id;
        if (dir == 0) { v = g_rval[b][spl][m]; id = g_ridx[b][spl][m]; }
        else          { v = g_cval[b][spl][m]; id = g_cidx[b][spl][m]; }
        #pragma unroll
        for (int off = 1; off < 8; off <<= 1) {
            float    ov = __shfl_xor(v, off);
            unsigned oi = __shfl_xor(id, off);
            if (ov < v || (ov == v && oi < id)) { v = ov; id = oi; }
        }
        if (spl == 0) s_rr[dir][b] = id;
    }
    __syncthreads();

    // gather rows: thread (bb, o) loads 8 floats of each mat's row
    const int o  = t & 15;               // c-octet
    const int bb = t >> 4;               // batch
    const unsigned rows[4] = { (unsigned)m, s_rr[0][bb], (unsigned)m, s_rr[1][bb] };
    #pragma unroll
    for (int mat = 0; mat < 4; ++mat) {
        const float* T = (mat == 0 || mat == 3) ? g_T[0] : g_T[1];
        const float* src = T + ((size_t)bb * NM + rows[mat]) * NC + o * 8;
        float4 v0 = *reinterpret_cast<const float4*>(src);
        float4 v1 = *reinterpret_cast<const float4*>(src + 4);
        *reinterpret_cast<float4*>(&Z[mat * 16 * ZS + bb * ZS + o * 8])     = v0;
        *reinterpret_cast<float4*>(&Z[mat * 16 * ZS + bb * ZS + o * 8 + 4]) = v1;
    }
    __syncthreads();

    // repr loss partial (uncentered)
    float racc = 0.f;
    #pragma unroll
    for (int i = 0; i < 8; ++i) {
        int idx = t + i * 256;
        int b = idx >> 7, c = idx & 127;
        float d0 = Z[0 * 16 * ZS + b * ZS + c] - Z[1 * 16 * ZS + b * ZS + c];
        float d1 = Z[2 * 16 * ZS + b * ZS + c] - Z[3 * 16 * ZS + b * ZS + c];
        racc += d0 * d0 + d1 * d1;
    }
    __syncthreads();                     // repr reads before centering writes

    // column stats: center in place, variance, std-loss, diag² accumulation
    float sacc = 0.f, qdacc = 0.f;
    #pragma unroll
    for (int pass = 0; pass < 2; ++pass) {
        int mat = (t >> 7) + pass * 2;
        int c   = t & 127;
        float* Zm = &Z[mat * 16 * ZS];
        float mu = 0.f;
        #pragma unroll
        for (int b = 0; b < 16; ++b) mu += Zm[b * ZS + c];
        mu *= 0.0625f;
        float d = 0.f;
        #pragma unroll
        for (int b = 0; b < 16; ++b) {
            float v = Zm[b * ZS + c] - mu;
            Zm[b * ZS + c] = v;
            d += v * v;
        }
        float stdv = sqrtf(d * (1.0f / 15.0f) + 1e-4f);
        sacc  += fmaxf(1.0f - stdv, 0.f);
        qdacc += d * d;
    }
    __syncthreads();

    // 16x16 Gram per matrix, symmetric c-split: thread (gi,gj) covers
    // c in [0,64) if gi<=gj else [64,128); diag covers all. G = P + P^T.
    const int gi = t >> 4, gj = t & 15;
    const int c0 = (gi <= gj) ? 0 : 64;
    const int c1 = (gi == gj) ? 128 : c0 + 64;
    float P[4];
    #pragma unroll
    for (int mat = 0; mat < 4; ++mat) {
        const float* Zi = &Z[mat * 16 * ZS + gi * ZS];
        const float* Zj = &Z[mat * 16 * ZS + gj * ZS];
        float g = 0.f;
        #pragma unroll 4
        for (int c = c0; c < c1; c += 4) {
            float4 a  = *reinterpret_cast<const float4*>(&Zi[c]);
            float4 bv = *reinterpret_cast<const float4*>(&Zj[c]);
            g += a.x * bv.x + a.y * bv.y + a.z * bv.z + a.w * bv.w;
        }
        P[mat] = g;
        sP[mat][gi][gj] = g;
    }
    __syncthreads();
    float qaacc = 0.f;
    #pragma unroll
    for (int mat = 0; mat < 4; ++mat) {
        float G = (gi == gj) ? P[mat] : (P[mat] + sP[mat][gj][gi]);
        qaacc += G * G;
    }

    // block-reduce the three partials
    float v0 = racc, v1 = sacc, v2 = qaacc - qdacc;
    #pragma unroll
    for (int off = 32; off >= 1; off >>= 1) {
        v0 += __shfl_xor(v0, off);
        v1 += __shfl_xor(v1, off);
        v2 += __shfl_xor(v2, off);
    }
    const int w = t >> 6;
    if ((t & 63) == 0) { red[w] = v0; red[4 + w] = v1; red[8 + w] = v2; }
    __syncthreads();
    if (t == 0) {
        g_part[0][m] = red[0] + red[1] + red[2] + red[3];
        g_part[1][m] = red[4] + red[5] + red[6] + red[7];
        g_part[2][m] = red[8] + red[9] + red[10] + red[11];
    }
}

// ---------------------------------------------------------------------------
__global__ __launch_bounds__(256)
void final_kernel(float* __restrict__ out)
{
    const int t = threadIdx.x;
    float r = 0.f, s = 0.f, q = 0.f;
    for (int i = t; i < NM; i += 256) {
        r += g_part[0][i];
        s += g_part[1][i];
        q += g_part[2][i];
    }
    __shared__ float red[12];
    #pragma unroll
    for (int off = 32; off >= 1; off >>= 1) {
        r += __shfl_xor(r, off);
        s += __shfl_xor(s, off);
        q += __shfl_xor(q, off);
    }
    const int w = t >> 6;
    if ((t & 63) == 0) { red[w] = r; red[4 + w] = s; red[8 + w] = q; }
    __syncthreads();
    if (t == 0) {
        r = red[0] + red[1] + red[2] + red[3];
        s = red[4] + red[5] + red[6] + red[7];
        q = red[8] + red[9] + red[10] + red[11];
        out[0] = r * (25.0f / 4194304.0f);
        out[1] = s * (25.0f / 524288.0f);
        out[2] = q * (1.0f / (225.0f * 1024.0f * 512.0f));
    }
}

// ---------------------------------------------------------------------------
extern "C" void kernel_launch(void* const* d_in, const int* in_sizes, int n_in,
                              void* d_out, int out_size, void* d_ws, size_t ws_size,
                              hipStream_t stream)
{
    const float* e1 = (const float*)d_in[0];
    const float* e2 = (const float*)d_in[1];
    float* out = (float*)d_out;

    transpose_kernel<<<dim3(16, 2, 32), 256, 0, stream>>>(e1, e2);
    argmin7_kernel<<<1024, 256, 0, stream>>>();
    loss_kernel<<<1024, 256, 0, stream>>>();
    final_kernel<<<1, 256, 0, stream>>>(out);
}